// Round 4
// baseline (440.145 us; speedup 1.0000x reference)
//
#include <hip/hip_runtime.h>
#include <cfloat>

#define BB 8
#define DD 256
#define NN 4096
#define TT 1024
constexpr float SCALE = 0.0625f;   // 1/sqrt(256)

typedef __attribute__((ext_vector_type(8))) short bf16x8;
typedef __attribute__((ext_vector_type(4))) float f32x4;
typedef __attribute__((ext_vector_type(8))) unsigned short u16x8;

__device__ inline unsigned short f2bf(float x) {
  union { float f; unsigned u; } v; v.f = x;
  unsigned r = v.u + 0x7fff + ((v.u >> 16) & 1);
  return (unsigned short)(r >> 16);
}
__device__ inline float bf2f(unsigned short h) {
  union { unsigned u; float f; } v; v.u = ((unsigned)h) << 16;
  return v.f;
}

__device__ inline void glds16(const unsigned short* g, const short* lbase) {
  __builtin_amdgcn_global_load_lds((const __attribute__((address_space(1))) unsigned int*)g,
                                   (__attribute__((address_space(3))) unsigned int*)lbase,
                                   16, 0, 0);
}
__device__ inline void glds16f(const float* g, const float* lbase) {
  __builtin_amdgcn_global_load_lds((const __attribute__((address_space(1))) unsigned int*)g,
                                   (__attribute__((address_space(3))) unsigned int*)lbase,
                                   16, 0, 0);
}

// raw barrier bracketed by scheduler fences so no LDS op can migrate across it
__device__ inline void wg_barrier() {
  __builtin_amdgcn_sched_barrier(0);
  __builtin_amdgcn_s_barrier();
  __builtin_amdgcn_sched_barrier(0);
}

// ---- ws layout (bytes) ----
#define MPART_OFF 0u                      // 8*32*1024 f = 1 MB
#define LPART_OFF (1u << 20)
#define IPART_OFF (2u << 20)
#define MARR_OFF  (3u << 20)
#define RLARR_OFF ((3u << 20) + 32768u)
#define CONV_OFF  (4u << 20)
#define KT_HI_OFF (CONV_OFF)
#define KT_LO_OFF (CONV_OFF + 16777216u)
#define QT_HI_OFF (CONV_OFF + 33554432u)
#define QT_LO_OFF (CONV_OFF + 37748736u)
#define VH_OFF    (CONV_OFF + 41943040u)
#define WS_NEED   (62914560ull)

// ---------------- convert+transpose+split ----------------
__global__ __launch_bounds__(256) void convert_t(const float* __restrict__ src,
                                                 unsigned short* __restrict__ dhi,
                                                 unsigned short* __restrict__ dlo,
                                                 int C) {
  __shared__ float tile[64][65];
  const int b = blockIdx.z, c0 = blockIdx.x * 64, d0 = blockIdx.y * 64;
  const int tid = threadIdx.x;
  const float* s = src + ((size_t)b * DD + d0) * C + c0;
  const int r = tid >> 4, cg = (tid & 15) * 4;
#pragma unroll
  for (int it = 0; it < 4; ++it) {
    float4 v = *(const float4*)(s + (size_t)(r + it * 16) * C + cg);
    tile[r + it * 16][cg + 0] = v.x; tile[r + it * 16][cg + 1] = v.y;
    tile[r + it * 16][cg + 2] = v.z; tile[r + it * 16][cg + 3] = v.w;
  }
  __syncthreads();
  const int cl = tid >> 2, dg = (tid & 3) * 16;
  unsigned short hi[16], lo[16];
#pragma unroll
  for (int j = 0; j < 16; ++j) {
    float x = tile[dg + j][cl];
    unsigned short h = f2bf(x);
    hi[j] = h;
    lo[j] = f2bf(x - bf2f(h));
  }
  size_t off = ((size_t)b * C + c0 + cl) * DD + d0 + dg;
  *(u16x8*)(dhi + off) = *(u16x8*)&hi[0];
  *(u16x8*)(dhi + off + 8) = *(u16x8*)&hi[8];
  *(u16x8*)(dlo + off) = *(u16x8*)&lo[0];
  *(u16x8*)(dlo + off + 8) = *(u16x8*)&lo[8];
}

__global__ __launch_bounds__(256) void convert_v(const float* __restrict__ src,
                                                 unsigned short* __restrict__ dhi) {
  size_t g = (size_t)blockIdx.x * 256 + threadIdx.x;
  float4 v = ((const float4*)src)[g];
  unsigned short h[4] = {f2bf(v.x), f2bf(v.y), f2bf(v.z), f2bf(v.w)};
  *(ushort4*)(dhi + g * 4) = *(ushort4*)h;
}

// ---------------- K1: S = scale*K^T Q (split-bf16 MFMA) + per-block softmax stats ----------------
// tile 128n x 128t, 4 waves; XCD-swizzled so each XCD owns one batch b
__global__ __launch_bounds__(256) void gemm_scores_mfma(const unsigned short* __restrict__ KtHi,
                                                        const unsigned short* __restrict__ KtLo,
                                                        const unsigned short* __restrict__ QtHi,
                                                        const unsigned short* __restrict__ QtLo,
                                                        float* __restrict__ S,
                                                        float* __restrict__ mPart,
                                                        float* __restrict__ lPart,
                                                        int* __restrict__ iPart) {
  __shared__ short sAhi[128 * 32];
  __shared__ short sAlo[128 * 32];
  __shared__ short sBhi[128 * 32];
  __shared__ short sBlo[128 * 32];
  __shared__ float sm[256], sl[256];
  __shared__ int si[256];

  // bijective XCD swizzle: 2048 blocks, 8 XCDs -> XCD k handles batch k
  const int lin = blockIdx.x + ((blockIdx.y + (blockIdx.z << 5)) << 3);
  const int wg = ((lin & 7) << 8) + (lin >> 3);
  const int b = wg >> 8;
  const int cy = (wg >> 3) & 31;          // n-chunk index
  const int n0 = cy * 128;
  const int t0 = (wg & 7) * 128;
  const int tid = threadIdx.x;
  const int lane = tid & 63, w = tid >> 6;
  const int nh = (w & 1) * 64, th = (w >> 1) * 64;
  const int fr = lane & 15, q = lane >> 4;

  const unsigned short* aHi = KtHi + ((size_t)b * NN + n0) * DD;
  const unsigned short* aLo = KtLo + ((size_t)b * NN + n0) * DD;
  const unsigned short* bHi = QtHi + ((size_t)b * TT + t0) * DD;
  const unsigned short* bLo = QtLo + ((size_t)b * TT + t0) * DD;

  f32x4 acc[4][4];
#pragma unroll
  for (int i = 0; i < 4; ++i)
#pragma unroll
    for (int j = 0; j < 4; ++j) acc[i][j] = (f32x4){0.f, 0.f, 0.f, 0.f};

  const int rowS = ((w * 64 + lane) & 127);
  const int kc0 = (w >> 1);
  const int lb0 = (0 * 256 + w * 64) * 8;
  const int lb1 = (1 * 256 + w * 64) * 8;

  for (int kk = 0; kk < DD; kk += 32) {
    glds16(aHi + (size_t)rowS * DD + kk + (kc0 + 0) * 8, sAhi + lb0);
    glds16(aHi + (size_t)rowS * DD + kk + (kc0 + 2) * 8, sAhi + lb1);
    glds16(aLo + (size_t)rowS * DD + kk + (kc0 + 0) * 8, sAlo + lb0);
    glds16(aLo + (size_t)rowS * DD + kk + (kc0 + 2) * 8, sAlo + lb1);
    glds16(bHi + (size_t)rowS * DD + kk + (kc0 + 0) * 8, sBhi + lb0);
    glds16(bHi + (size_t)rowS * DD + kk + (kc0 + 2) * 8, sBhi + lb1);
    glds16(bLo + (size_t)rowS * DD + kk + (kc0 + 0) * 8, sBlo + lb0);
    glds16(bLo + (size_t)rowS * DD + kk + (kc0 + 2) * 8, sBlo + lb1);
    __syncthreads();

    bf16x8 bh[4], bl[4];
#pragma unroll
    for (int tb = 0; tb < 4; ++tb) {
      int off = q * 1024 + (th + tb * 16 + fr) * 8;
      bh[tb] = *(const bf16x8*)&sBhi[off];
      bl[tb] = *(const bf16x8*)&sBlo[off];
    }
#pragma unroll
    for (int mb = 0; mb < 4; ++mb) {
      int off = q * 1024 + (nh + mb * 16 + fr) * 8;
      bf16x8 ah = *(const bf16x8*)&sAhi[off];
      bf16x8 al = *(const bf16x8*)&sAlo[off];
#pragma unroll
      for (int tb = 0; tb < 4; ++tb) {
        acc[mb][tb] = __builtin_amdgcn_mfma_f32_16x16x32_bf16(ah, bh[tb], acc[mb][tb], 0, 0, 0);
        acc[mb][tb] = __builtin_amdgcn_mfma_f32_16x16x32_bf16(ah, bl[tb], acc[mb][tb], 0, 0, 0);
        acc[mb][tb] = __builtin_amdgcn_mfma_f32_16x16x32_bf16(al, bh[tb], acc[mb][tb], 0, 0, 0);
      }
    }
    __syncthreads();
  }

#pragma unroll
  for (int tb = 0; tb < 4; ++tb) {
    const int tl = th + tb * 16 + fr;
    const int t = t0 + tl;
    float tmp[16];
    float m = -FLT_MAX; int id = 0;
#pragma unroll
    for (int mb = 0; mb < 4; ++mb)
#pragma unroll
      for (int r = 0; r < 4; ++r) {
        float v = acc[mb][tb][r] * SCALE;
        int n = n0 + nh + mb * 16 + q * 4 + r;
        S[((size_t)b * NN + n) * TT + t] = v;
        tmp[mb * 4 + r] = v;
        int nl = nh + mb * 16 + q * 4 + r;
        if (v > m) { m = v; id = nl; }
      }
    float l = 0.f;
#pragma unroll
    for (int j = 0; j < 16; ++j) l += __expf(tmp[j] - m);
#pragma unroll
    for (int off = 16; off <= 32; off <<= 1) {
      float m2 = __shfl_xor(m, off);
      float l2 = __shfl_xor(l, off);
      int i2 = __shfl_xor(id, off);
      if (m2 > m)       { l = l * __expf(m - m2) + l2; m = m2; id = i2; }
      else if (m2 == m) { l += l2; id = min(id, i2); }
      else              { l += l2 * __expf(m2 - m); }
    }
    if (q == 0) {
      int slot = (w & 1) * 128 + tl;
      sm[slot] = m; sl[slot] = l; si[slot] = id;
    }
  }
  __syncthreads();
  if (tid < 128) {
    float m = sm[tid], l = sl[tid]; int id = si[tid];
    float m2 = sm[128 + tid], l2 = sl[128 + tid]; int i2 = si[128 + tid];
    if (m2 > m)       { l = l * __expf(m - m2) + l2; m = m2; id = i2; }
    else if (m2 == m) { l += l2; id = min(id, i2); }
    else              { l += l2 * __expf(m2 - m); }
    size_t p = ((size_t)b * 32 + cy) * TT + t0 + tid;
    mPart[p] = m; lPart[p] = l; iPart[p] = n0 + id;
  }
}

// ---------------- K3: fused stats-final + A=exp(S-m)*rl + R=V@A (full N) + argmax + Q-copy ----------------
// grid (T/32, B) = 256 blocks (1/CU). ALL in-loop VMEM is register-destination-free:
// V and raw-A are staged 3 chunks ahead via global_load_lds (4-deep LDS buffers); the only
// loop waits are the counted s_waitcnt vmcnt(18) (3 iterations of VMEM stay in flight).
// sV/sAraw are wave-self-contained (each wave stages exactly what it reads) -> the 2
// barriers per iter protect only the tiny cross-wave sA tile.
__global__ __launch_bounds__(256) void gemm_out_full(const unsigned short* __restrict__ Vh,
                                                     float* __restrict__ A,   // in: raw S, out: normalized
                                                     const float* __restrict__ mPart,
                                                     const float* __restrict__ lPart,
                                                     const int* __restrict__ iPart,
                                                     const float* __restrict__ Qp,
                                                     float* __restrict__ out,
                                                     float* __restrict__ outMax) {
  __shared__ short sV[4][256 * 32];     // [buf][kc][d][8], 4 x 16 KB
  __shared__ float sAraw[4][1024];      // [buf][tid*4], 4 x 4 KB raw S staging
  __shared__ short sA[32 * 40];         // [t][n] pad 40
  __shared__ float rsm[8][32], rsl[8][32];
  __shared__ int   rsi[8][32];
  __shared__ float sm[32], srl[32];

  // bijective XCD swizzle: 256 blocks -> XCD k owns batch k (V[b] stays L2-resident)
  const int lin = blockIdx.x + (blockIdx.y << 5);
  const int wg = ((lin & 7) << 5) + (lin >> 3);
  const int b = wg >> 5;
  const int t0 = (wg & 31) * 32;

  const int tid = threadIdx.x;
  const int lane = tid & 63, w = tid >> 6;
  const int fr = lane & 15, q = lane >> 4, fk = q * 8;
  const int sn = tid >> 3, tg = tid & 7;
  const int vd = w * 64 + lane;

  const unsigned short* Vb = Vh + (size_t)b * DD * NN;
  float* Ab = A + (size_t)b * NN * TT;
  float* Arow = Ab + (size_t)sn * TT + t0 + tg * 4;
  const float* sAmy = &sAraw[0][0] + tid * 4;        // this thread's staged float4 (buf 0)
  const float* wArawBase = &sAraw[0][0] + w * 256;   // wave-uniform LDS base for glds

  // prologue: stage chunks 0..2 (V + raw A); latency hides under Q-copy/stats below,
  // and the stats-section vmcnt(0)+barrier guarantees completion.
#pragma unroll
  for (int pc = 0; pc < 3; ++pc) {
#pragma unroll
    for (int c = 0; c < 4; ++c)
      glds16(Vb + (size_t)vd * NN + pc * 32 + c * 8, &sV[pc][(c * 256 + w * 64) * 8]);
    glds16f(Arow + (size_t)(pc * 32) * TT, wArawBase + pc * 1024);
  }

  // Q-copy: out rows 256..511 for this t-slice
  {
    const int tq = tid & 7, rq = tid >> 3;
#pragma unroll
    for (int it = 0; it < 8; ++it) {
      const int d = it * 32 + rq;
      float4 v = *(const float4*)(Qp + ((size_t)b * DD + d) * TT + t0 + tq * 4);
      *(float4*)(out + ((size_t)b * 2 * DD + DD + d) * TT + t0 + tq * 4) = v;
    }
  }

  // stats final: merge the 32 chunk partials for this block's 32 t's (8-way parallel per t)
  {
    const int tl = tid & 31, g = tid >> 5;
    float m = -FLT_MAX, l = 0.f; int idx = 0;
#pragma unroll
    for (int cc = 0; cc < 4; ++cc) {
      size_t p = ((size_t)b * 32 + g * 4 + cc) * TT + t0 + tl;
      float m2 = mPart[p], l2 = lPart[p]; int i2 = iPart[p];
      if (m2 > m)       { l = l * __expf(m - m2) + l2; m = m2; idx = i2; }
      else if (m2 == m) { l += l2; idx = min(idx, i2); }
      else              { l += l2 * __expf(m2 - m); }
    }
    rsm[g][tl] = m; rsl[g][tl] = l; rsi[g][tl] = idx;
  }
  __syncthreads();
  if (tid < 32) {
    float m = rsm[0][tid], l = rsl[0][tid]; int idx = rsi[0][tid];
#pragma unroll
    for (int g = 1; g < 8; ++g) {
      float m2 = rsm[g][tid], l2 = rsl[g][tid]; int i2 = rsi[g][tid];
      if (m2 > m)       { l = l * __expf(m - m2) + l2; m = m2; idx = i2; }
      else if (m2 == m) { l += l2; idx = min(idx, i2); }
      else              { l += l2 * __expf(m2 - m); }
    }
    sm[tid] = m; srl[tid] = 1.0f / l;
    outMax[(size_t)b * TT + t0 + tid] = (float)idx;
  }
  // drain prologue staging (also covered by the barrier's own drain semantics)
  asm volatile("s_waitcnt vmcnt(0)" ::: "memory");
  __syncthreads();

  const float4 mv = *(const float4*)&sm[tg * 4];
  const float4 rv = *(const float4*)&srl[tg * 4];

  f32x4 acc[4][2];
#pragma unroll
  for (int i = 0; i < 4; ++i) { acc[i][0] = (f32x4){0,0,0,0}; acc[i][1] = (f32x4){0,0,0,0}; }

  // main loop over chunks t=0..124 (last 3 peeled). Per-iter VMEM (in order) =
  // [4 glds V(t+3), 1 glds Araw(t+3)] ... [1 global_store A(t)] -> 6 ops, none with a
  // register destination. Ops after glds(t)'s last (issued at iter t-3):
  // 1 (store t-3) + 6 + 6 + 5 (this iter's glds) = 18 -> vmcnt(18) ensures chunk t is
  // LDS-resident while keeping ~3 iterations of VMEM permanently in flight.
  for (int nn = 0; nn < NN - 96; nn += 32) {
    const int t = nn >> 5;
    const int bi = t & 3, bn = (t + 3) & 3;
    short* sVn = &sV[bn][0];
#pragma unroll
    for (int c = 0; c < 4; ++c)
      glds16(Vb + (size_t)vd * NN + (nn + 96) + c * 8, sVn + (c * 256 + w * 64) * 8);
    glds16f(Arow + (size_t)(nn + 96) * TT, wArawBase + bn * 1024);

    __builtin_amdgcn_sched_barrier(0);
    asm volatile("s_waitcnt vmcnt(18)" ::: "memory");
    __builtin_amdgcn_sched_barrier(0);

    // own-thread raw A readback (wave-private: no barrier needed)
    float4 cur = *(const float4*)(sAmy + bi * 1024);
    float4 av;
    av.x = __expf(cur.x - mv.x) * rv.x;
    av.y = __expf(cur.y - mv.y) * rv.y;
    av.z = __expf(cur.z - mv.z) * rv.z;
    av.w = __expf(cur.w - mv.w) * rv.w;
    *(float4*)(Arow + (size_t)nn * TT) = av;
    sA[(tg * 4 + 0) * 40 + sn] = (short)f2bf(av.x);
    sA[(tg * 4 + 1) * 40 + sn] = (short)f2bf(av.y);
    sA[(tg * 4 + 2) * 40 + sn] = (short)f2bf(av.z);
    sA[(tg * 4 + 3) * 40 + sn] = (short)f2bf(av.w);

    asm volatile("s_waitcnt lgkmcnt(0)" ::: "memory");
    wg_barrier();                                    // barrier1: sA ready

    bf16x8 bf0 = *(const bf16x8*)&sA[(0 * 16 + fr) * 40 + fk];
    bf16x8 bf1 = *(const bf16x8*)&sA[(1 * 16 + fr) * 40 + fk];
#pragma unroll
    for (int mb = 0; mb < 4; ++mb) {
      bf16x8 af = *(const bf16x8*)&sV[bi][q * 2048 + (w * 64 + mb * 16 + fr) * 8];
      acc[mb][0] = __builtin_amdgcn_mfma_f32_16x16x32_bf16(af, bf0, acc[mb][0], 0, 0, 0);
      acc[mb][1] = __builtin_amdgcn_mfma_f32_16x16x32_bf16(af, bf1, acc[mb][1], 0, 0, 0);
    }
    wg_barrier();                                    // barrier2: sA reads done before next write
  }

  // peeled last 3 chunks (no more staging; cheap full drain)
#pragma unroll
  for (int pt = 0; pt < 3; ++pt) {
    const int nn = NN - 96 + pt * 32;
    const int t = nn >> 5;
    const int bi = t & 3;

    __builtin_amdgcn_sched_barrier(0);
    asm volatile("s_waitcnt vmcnt(0)" ::: "memory");
    __builtin_amdgcn_sched_barrier(0);

    float4 cur = *(const float4*)(sAmy + bi * 1024);
    float4 av;
    av.x = __expf(cur.x - mv.x) * rv.x;
    av.y = __expf(cur.y - mv.y) * rv.y;
    av.z = __expf(cur.z - mv.z) * rv.z;
    av.w = __expf(cur.w - mv.w) * rv.w;
    *(float4*)(Arow + (size_t)nn * TT) = av;
    sA[(tg * 4 + 0) * 40 + sn] = (short)f2bf(av.x);
    sA[(tg * 4 + 1) * 40 + sn] = (short)f2bf(av.y);
    sA[(tg * 4 + 2) * 40 + sn] = (short)f2bf(av.z);
    sA[(tg * 4 + 3) * 40 + sn] = (short)f2bf(av.w);

    asm volatile("s_waitcnt lgkmcnt(0)" ::: "memory");
    wg_barrier();

    bf16x8 bf0 = *(const bf16x8*)&sA[(0 * 16 + fr) * 40 + fk];
    bf16x8 bf1 = *(const bf16x8*)&sA[(1 * 16 + fr) * 40 + fk];
#pragma unroll
    for (int mb = 0; mb < 4; ++mb) {
      bf16x8 af = *(const bf16x8*)&sV[bi][q * 2048 + (w * 64 + mb * 16 + fr) * 8];
      acc[mb][0] = __builtin_amdgcn_mfma_f32_16x16x32_bf16(af, bf0, acc[mb][0], 0, 0, 0);
      acc[mb][1] = __builtin_amdgcn_mfma_f32_16x16x32_bf16(af, bf1, acc[mb][1], 0, 0, 0);
    }
    wg_barrier();
  }

  // epilogue: write R_ top half directly (full-N accumulation, no Rpart/combine)
#pragma unroll
  for (int mb = 0; mb < 4; ++mb)
#pragma unroll
    for (int tb = 0; tb < 2; ++tb) {
      const int t = t0 + tb * 16 + fr;
#pragma unroll
      for (int r = 0; r < 4; ++r) {
        const int d = w * 64 + mb * 16 + q * 4 + r;
        out[((size_t)b * 2 * DD + d) * TT + t] = acc[mb][tb][r];
      }
    }
}

// =================== fp32 fallback path (ws too small) ===================
__global__ __launch_bounds__(256) void gemm_scores_fp32(const float* __restrict__ Kp,
                                                        const float* __restrict__ Qp,
                                                        float* __restrict__ S) {
  const int b = blockIdx.z;
  const int n0 = blockIdx.y * 128;
  const int t0 = blockIdx.x * 128;
  const int tid = threadIdx.x;
  const int tx = tid & 15, ty = tid >> 4;
  __shared__ float Kt[8][128];
  __shared__ float Qt[8][128];
  float acc[8][8];
#pragma unroll
  for (int i = 0; i < 8; ++i)
#pragma unroll
    for (int j = 0; j < 8; ++j) acc[i][j] = 0.f;
  const int lin = tid * 4;
  const int lkk = lin >> 7, lcol = lin & 127;
  const float* Kbase = Kp + (size_t)b * DD * NN;
  const float* Qbase = Qp + (size_t)b * DD * TT;
  for (int dd0 = 0; dd0 < DD; dd0 += 8) {
    float4 kv = *(const float4*)(Kbase + (size_t)(dd0 + lkk) * NN + n0 + lcol);
    float4 qv = *(const float4*)(Qbase + (size_t)(dd0 + lkk) * TT + t0 + lcol);
    __syncthreads();
    *(float4*)&Kt[lkk][lcol] = kv;
    *(float4*)&Qt[lkk][lcol] = qv;
    __syncthreads();
#pragma unroll
    for (int kk = 0; kk < 8; ++kk) {
      float4 a0 = *(float4*)&Kt[kk][ty * 4];
      float4 a1 = *(float4*)&Kt[kk][64 + ty * 4];
      float4 b0 = *(float4*)&Qt[kk][tx * 4];
      float4 b1 = *(float4*)&Qt[kk][64 + tx * 4];
      float av[8] = {a0.x, a0.y, a0.z, a0.w, a1.x, a1.y, a1.z, a1.w};
      float bv[8] = {b0.x, b0.y, b0.z, b0.w, b1.x, b1.y, b1.z, b1.w};
#pragma unroll
      for (int i = 0; i < 8; ++i)
#pragma unroll
        for (int j = 0; j < 8; ++j) acc[i][j] += av[i] * bv[j];
    }
  }
#pragma unroll
  for (int i = 0; i < 8; ++i) {
    int r = n0 + ((i < 4) ? (ty * 4 + i) : (64 + ty * 4 + i - 4));
    float* dst = S + ((size_t)b * NN + r) * TT + t0;
    *(float4*)(dst + tx * 4) = make_float4(acc[i][0] * SCALE, acc[i][1] * SCALE, acc[i][2] * SCALE, acc[i][3] * SCALE);
    *(float4*)(dst + 64 + tx * 4) = make_float4(acc[i][4] * SCALE, acc[i][5] * SCALE, acc[i][6] * SCALE, acc[i][7] * SCALE);
  }
}

__global__ __launch_bounds__(256) void stats_partial_fb(const float* __restrict__ S,
                                                        float* __restrict__ mPart,
                                                        float* __restrict__ lPart,
                                                        int* __restrict__ iPart) {
  const int tid = threadIdx.x;
  const int tx = tid & 63, ty = tid >> 6;
  const int b = blockIdx.z;
  const int t = blockIdx.x * 64 + tx;
  const int nbase = blockIdx.y * 512;
  float m = -FLT_MAX, l = 0.f;
  int idx = 0;
  const float* col = S + (size_t)b * NN * TT + t;
  for (int n = nbase + ty; n < nbase + 512; n += 4) {
    float s = col[(size_t)n * TT];
    if (s > m) { l = l * __expf(m - s) + 1.0f; m = s; idx = n; }
    else        l += __expf(s - m);
  }
  __shared__ float sm[4][64], sl[4][64];
  __shared__ int si[4][64];
  sm[ty][tx] = m; sl[ty][tx] = l; si[ty][tx] = idx;
  __syncthreads();
  if (ty == 0) {
#pragma unroll
    for (int k = 1; k < 4; ++k) {
      float m2 = sm[k][tx], l2 = sl[k][tx];
      int i2 = si[k][tx];
      if (m2 > m)       { l = l * __expf(m - m2) + l2; m = m2; idx = i2; }
      else if (m2 == m) { l += l2; idx = min(idx, i2); }
      else              { l += l2 * __expf(m2 - m); }
    }
    size_t p = (size_t)(b * 8 + blockIdx.y) * TT + t;
    mPart[p] = m; lPart[p] = l; iPart[p] = idx;
  }
}

__global__ __launch_bounds__(256) void stats_final_fb(const float* __restrict__ mPart,
                                                      const float* __restrict__ lPart,
                                                      const int* __restrict__ iPart,
                                                      float* __restrict__ mArr,
                                                      float* __restrict__ rlArr,
                                                      float* __restrict__ outMax) {
  int col = blockIdx.x * 256 + threadIdx.x;
  int b = col >> 10, t = col & 1023;
  float m = -FLT_MAX, l = 0.f;
  int idx = 0;
#pragma unroll
  for (int c = 0; c < 8; ++c) {
    size_t p = (size_t)(b * 8 + c) * TT + t;
    float m2 = mPart[p], l2 = lPart[p];
    int i2 = iPart[p];
    if (m2 > m)       { l = l * __expf(m - m2) + l2; m = m2; idx = i2; }
    else if (m2 == m) { l += l2; idx = min(idx, i2); }
    else              { l += l2 * __expf(m2 - m); }
  }
  mArr[col] = m;
  rlArr[col] = 1.0f / l;
  outMax[col] = (float)idx;
}

__global__ __launch_bounds__(256) void normalize_fb(float* __restrict__ A,
                                                    const float* __restrict__ mArr,
                                                    const float* __restrict__ rlArr) {
  int g = blockIdx.x * 256 + threadIdx.x;
  float4 s = ((const float4*)A)[g];
  int e = g * 4;
  int t0 = e & 1023;
  int row = e >> 10;
  int b = row >> 12;
  int cb = (b << 10) + t0;
  float4 r;
  r.x = __expf(s.x - mArr[cb + 0]) * rlArr[cb + 0];
  r.y = __expf(s.y - mArr[cb + 1]) * rlArr[cb + 1];
  r.z = __expf(s.z - mArr[cb + 2]) * rlArr[cb + 2];
  r.w = __expf(s.w - mArr[cb + 3]) * rlArr[cb + 3];
  ((float4*)A)[g] = r;
}

__global__ __launch_bounds__(256) void gemm_out_fp32(const float* __restrict__ Vp,
                                                     const float* __restrict__ A,
                                                     float* __restrict__ Rout) {
  const int b = blockIdx.z;
  const int m0 = blockIdx.y * 64;
  const int t0 = blockIdx.x * 128;
  const int tid = threadIdx.x;
  const int tx = tid & 15, ty = tid >> 4;
  __shared__ float Vt[16][68];
  __shared__ float At[16][128];
  float acc[4][8];
#pragma unroll
  for (int i = 0; i < 4; ++i)
#pragma unroll
    for (int j = 0; j < 8; ++j) acc[i][j] = 0.f;
  const float* Vbase = Vp + (size_t)b * DD * NN;
  const float* Abase = A + (size_t)b * NN * TT;
  const int vmm = tid >> 2, vkk = (tid & 3) * 4;
  const int akk = tid >> 5, att = (tid * 4) & 127;
  for (int nn0 = 0; nn0 < NN; nn0 += 16) {
    float4 vv = *(const float4*)(Vbase + (size_t)(m0 + vmm) * NN + nn0 + vkk);
    float4 a0 = *(const float4*)(Abase + (size_t)(nn0 + akk) * TT + t0 + att);
    float4 a1 = *(const float4*)(Abase + (size_t)(nn0 + akk + 8) * TT + t0 + att);
    __syncthreads();
    Vt[vkk + 0][vmm] = vv.x; Vt[vkk + 1][vmm] = vv.y;
    Vt[vkk + 2][vmm] = vv.z; Vt[vkk + 3][vmm] = vv.w;
    *(float4*)&At[akk][att] = a0;
    *(float4*)&At[akk + 8][att] = a1;
    __syncthreads();
#pragma unroll
    for (int kk = 0; kk < 16; ++kk) {
      float4 a4 = *(float4*)&Vt[kk][ty * 4];
      float4 b0 = *(float4*)&At[kk][tx * 4];
      float4 b1 = *(float4*)&At[kk][64 + tx * 4];
      float av[4] = {a4.x, a4.y, a4.z, a4.w};
      float bv[8] = {b0.x, b0.y, b0.z, b0.w, b1.x, b1.y, b1.z, b1.w};
#pragma unroll
      for (int i = 0; i < 4; ++i)
#pragma unroll
        for (int j = 0; j < 8; ++j) acc[i][j] += av[i] * bv[j];
    }
  }
#pragma unroll
  for (int i = 0; i < 4; ++i) {
    int r = m0 + ty * 4 + i;
    float* dst = Rout + (size_t)b * (2 * DD) * TT + (size_t)r * TT + t0;
    *(float4*)(dst + tx * 4) = make_float4(acc[i][0], acc[i][1], acc[i][2], acc[i][3]);
    *(float4*)(dst + 64 + tx * 4) = make_float4(acc[i][4], acc[i][5], acc[i][6], acc[i][7]);
  }
}

__global__ __launch_bounds__(256) void qcopy(const float* __restrict__ Qp,
                                             float* __restrict__ out) {
  int g = blockIdx.x * 256 + threadIdx.x;
  int e = g * 4;
  int t0 = e & 1023;
  int row = e >> 10;
  int dd = row & 255, b = row >> 8;
  float4 v = ((const float4*)Qp)[g];
  *(float4*)(out + (size_t)b * 512 * TT + (size_t)(256 + dd) * TT + t0) = v;
}

extern "C" void kernel_launch(void* const* d_in, const int* in_sizes, int n_in,
                              void* d_out, int out_size, void* d_ws, size_t ws_size,
                              hipStream_t stream) {
  const float* Kp = (const float*)d_in[0];
  const float* Vp = (const float*)d_in[1];
  const float* Qp = (const float*)d_in[2];
  float* out = (float*)d_out;
  float* R_ = out;
  float* A = out + 4194304;
  float* outMax = out + 4194304 + 33554432;

  char* wsb = (char*)d_ws;
  float* mPart = (float*)(wsb + MPART_OFF);
  float* lPart = (float*)(wsb + LPART_OFF);
  int*   iPart = (int*)(wsb + IPART_OFF);
  float* mArr  = (float*)(wsb + MARR_OFF);
  float* rlArr = (float*)(wsb + RLARR_OFF);

  const bool fast = (ws_size >= WS_NEED);

  if (fast) {
    unsigned short* KtHi = (unsigned short*)(wsb + KT_HI_OFF);
    unsigned short* KtLo = (unsigned short*)(wsb + KT_LO_OFF);
    unsigned short* QtHi = (unsigned short*)(wsb + QT_HI_OFF);
    unsigned short* QtLo = (unsigned short*)(wsb + QT_LO_OFF);
    unsigned short* Vh   = (unsigned short*)(wsb + VH_OFF);

    convert_t<<<dim3(NN / 64, 4, BB), 256, 0, stream>>>(Kp, KtHi, KtLo, NN);
    convert_t<<<dim3(TT / 64, 4, BB), 256, 0, stream>>>(Qp, QtHi, QtLo, TT);
    convert_v<<<dim3((BB * DD * NN / 4) / 256), 256, 0, stream>>>(Vp, Vh);
    gemm_scores_mfma<<<dim3(TT / 128, NN / 128, BB), 256, 0, stream>>>(
        KtHi, KtLo, QtHi, QtLo, A, mPart, lPart, iPart);
    gemm_out_full<<<dim3(TT / 32, BB), 256, 0, stream>>>(
        Vh, A, mPart, lPart, iPart, Qp, R_, outMax);
  } else {
    gemm_scores_fp32<<<dim3(TT / 128, NN / 128, BB), 256, 0, stream>>>(Kp, Qp, A);
    stats_partial_fb<<<dim3(TT / 64, NN / 512, BB), 256, 0, stream>>>(A, mPart, lPart, iPart);
    stats_final_fb<<<dim3(32), 256, 0, stream>>>(mPart, lPart, iPart, mArr, rlArr, outMax);
    normalize_fb<<<dim3((BB * NN * TT / 4) / 256), 256, 0, stream>>>(A, mArr, rlArr);
    gemm_out_fp32<<<dim3(TT / 128, DD / 64, BB), 256, 0, stream>>>(Vp, A, R_);
    qcopy<<<dim3((BB * DD * TT / 4) / 256), 256, 0, stream>>>(Qp, R_);
  }
}

// Round 5
// 334.236 us; speedup vs baseline: 1.3169x; 1.3169x over previous
//
#include <hip/hip_runtime.h>
#include <cfloat>

#define BB 8
#define DD 256
#define NN 4096
#define TT 1024
constexpr float SCALE = 0.0625f;   // 1/sqrt(256)

typedef __attribute__((ext_vector_type(8))) short bf16x8;
typedef __attribute__((ext_vector_type(4))) float f32x4;
typedef __attribute__((ext_vector_type(8))) unsigned short u16x8;

__device__ inline unsigned short f2bf(float x) {
  union { float f; unsigned u; } v; v.f = x;
  unsigned r = v.u + 0x7fff + ((v.u >> 16) & 1);
  return (unsigned short)(r >> 16);
}
__device__ inline float bf2f(unsigned short h) {
  union { unsigned u; float f; } v; v.u = ((unsigned)h) << 16;
  return v.f;
}

__device__ inline void glds16(const unsigned short* g, const short* lbase) {
  __builtin_amdgcn_global_load_lds((const __attribute__((address_space(1))) unsigned int*)g,
                                   (__attribute__((address_space(3))) unsigned int*)lbase,
                                   16, 0, 0);
}

// raw barrier bracketed by scheduler fences
__device__ inline void wg_barrier() {
  __builtin_amdgcn_sched_barrier(0);
  __builtin_amdgcn_s_barrier();
  __builtin_amdgcn_sched_barrier(0);
}

// ---- ws layout (bytes) ----
#define MPART_OFF 0u                      // 8*32*1024 f = 1 MB
#define LPART_OFF (1u << 20)
#define IPART_OFF (2u << 20)
#define MARR_OFF  (3u << 20)
#define RLARR_OFF ((3u << 20) + 32768u)
#define CONV_OFF  (4u << 20)
#define KT_HI_OFF (CONV_OFF)
#define KT_LO_OFF (CONV_OFF + 16777216u)
#define QT_HI_OFF (CONV_OFF + 33554432u)
#define QT_LO_OFF (CONV_OFF + 37748736u)
#define VH_OFF    (CONV_OFF + 41943040u)
#define RPART_OFF (CONV_OFF)              // aliases Kt hi/lo (dead after gemm_scores)
#define WS_NEED   (62914560ull)

// ---------------- convert+transpose+split (K and Q in one launch) ----------------
__global__ __launch_bounds__(256) void convert_t2(const float* __restrict__ Ksrc,
                                                  const float* __restrict__ Qsrc,
                                                  unsigned short* __restrict__ KHi,
                                                  unsigned short* __restrict__ KLo,
                                                  unsigned short* __restrict__ QHi,
                                                  unsigned short* __restrict__ QLo) {
  __shared__ float tile[64][65];
  const int bx = blockIdx.x;
  const int b = blockIdx.z, d0 = blockIdx.y * 64;
  const float* src; unsigned short* dhi; unsigned short* dlo; int C; int c0;
  if (bx < 64) { src = Ksrc; dhi = KHi; dlo = KLo; C = NN; c0 = bx * 64; }
  else         { src = Qsrc; dhi = QHi; dlo = QLo; C = TT; c0 = (bx - 64) * 64; }
  const int tid = threadIdx.x;
  const float* s = src + ((size_t)b * DD + d0) * C + c0;
  const int r = tid >> 4, cg = (tid & 15) * 4;
#pragma unroll
  for (int it = 0; it < 4; ++it) {
    float4 v = *(const float4*)(s + (size_t)(r + it * 16) * C + cg);
    tile[r + it * 16][cg + 0] = v.x; tile[r + it * 16][cg + 1] = v.y;
    tile[r + it * 16][cg + 2] = v.z; tile[r + it * 16][cg + 3] = v.w;
  }
  __syncthreads();
  const int cl = tid >> 2, dg = (tid & 3) * 16;
  unsigned short hi[16], lo[16];
#pragma unroll
  for (int j = 0; j < 16; ++j) {
    float x = tile[dg + j][cl];
    unsigned short h = f2bf(x);
    hi[j] = h;
    lo[j] = f2bf(x - bf2f(h));
  }
  size_t off = ((size_t)b * C + c0 + cl) * DD + d0 + dg;
  *(u16x8*)(dhi + off) = *(u16x8*)&hi[0];
  *(u16x8*)(dhi + off + 8) = *(u16x8*)&hi[8];
  *(u16x8*)(dlo + off) = *(u16x8*)&lo[0];
  *(u16x8*)(dlo + off + 8) = *(u16x8*)&lo[8];
}

__global__ __launch_bounds__(256) void convert_v(const float* __restrict__ src,
                                                 unsigned short* __restrict__ dhi) {
  size_t g = (size_t)blockIdx.x * 256 + threadIdx.x;
  float4 v = ((const float4*)src)[g];
  unsigned short h[4] = {f2bf(v.x), f2bf(v.y), f2bf(v.z), f2bf(v.w)};
  *(ushort4*)(dhi + g * 4) = *(ushort4*)h;
}

// ---------------- K1: S = scale*K^T Q (split-bf16 MFMA) + per-block softmax stats ----------------
// Line-contiguous glds staging: each glds = 16 rows x 64B (4 lanes per 64B line) with
// quad-XOR source pre-swizzle; LDS layout [row][64B] linear, reads 2 lanes/bank.
__global__ __launch_bounds__(256) void gemm_scores_mfma(const unsigned short* __restrict__ KtHi,
                                                        const unsigned short* __restrict__ KtLo,
                                                        const unsigned short* __restrict__ QtHi,
                                                        const unsigned short* __restrict__ QtLo,
                                                        float* __restrict__ S,
                                                        float* __restrict__ mPart,
                                                        float* __restrict__ lPart,
                                                        int* __restrict__ iPart) {
  __shared__ __align__(16) short sAhi[128 * 32];
  __shared__ __align__(16) short sAlo[128 * 32];
  __shared__ __align__(16) short sBhi[128 * 32];
  __shared__ __align__(16) short sBlo[128 * 32];
  __shared__ float sm[256], sl[256];
  __shared__ int si[256];

  // bijective XCD swizzle: 2048 blocks, XCD k handles batch k
  const int lin = blockIdx.x + ((blockIdx.y + (blockIdx.z << 5)) << 3);
  const int wg = ((lin & 7) << 8) + (lin >> 3);
  const int b = wg >> 8;
  const int cy = (wg >> 3) & 31;
  const int n0 = cy * 128;
  const int t0 = (wg & 7) * 128;
  const int tid = threadIdx.x;
  const int lane = tid & 63, w = tid >> 6;
  const int nh = (w & 1) * 64, th = (w >> 1) * 64;
  const int fr = lane & 15, q = lane >> 4;

  const unsigned short* aHi = KtHi + ((size_t)b * NN + n0) * DD;
  const unsigned short* aLo = KtLo + ((size_t)b * NN + n0) * DD;
  const unsigned short* bHi = QtHi + ((size_t)b * TT + t0) * DD;
  const unsigned short* bLo = QtLo + ((size_t)b * TT + t0) * DD;

  f32x4 acc[4][4];
#pragma unroll
  for (int i = 0; i < 4; ++i)
#pragma unroll
    for (int j = 0; j < 4; ++j) acc[i][j] = (f32x4){0.f, 0.f, 0.f, 0.f};

  // staging geometry: group g = w*2+c covers rows g*16..+15; lane: row-in-group R = l>>2,
  // stored pos P = l&3 holds quad Q = P ^ ((R>>1)&3). 4 consecutive lanes = one 64B line.
  const int R = lane >> 2;
  const int Qq = (lane & 3) ^ ((lane >> 3) & 3);
  const size_t s0 = (size_t)((w * 2 + 0) * 16 + R) * DD + Qq * 8;
  const size_t s1 = (size_t)((w * 2 + 1) * 16 + R) * DD + Qq * 8;
  const int d0 = (w * 2 + 0) * 512;   // shorts (1KB per group)
  const int d1 = (w * 2 + 1) * 512;
  const int pq8 = (q ^ ((fr >> 1) & 3)) * 8;   // read-side pos for quad q at row fr

  for (int kk = 0; kk < DD; kk += 32) {
    glds16(aHi + s0 + kk, sAhi + d0);
    glds16(aHi + s1 + kk, sAhi + d1);
    glds16(aLo + s0 + kk, sAlo + d0);
    glds16(aLo + s1 + kk, sAlo + d1);
    glds16(bHi + s0 + kk, sBhi + d0);
    glds16(bHi + s1 + kk, sBhi + d1);
    glds16(bLo + s0 + kk, sBlo + d0);
    glds16(bLo + s1 + kk, sBlo + d1);
    __syncthreads();

    bf16x8 bh[4], bl[4];
#pragma unroll
    for (int tb = 0; tb < 4; ++tb) {
      int off = (((w >> 1) * 4 + tb) * 512) + fr * 32 + pq8;   // row th+tb*16+fr, quad q
      bh[tb] = *(const bf16x8*)&sBhi[off];
      bl[tb] = *(const bf16x8*)&sBlo[off];
    }
#pragma unroll
    for (int mb = 0; mb < 4; ++mb) {
      int off = (((w & 1) * 4 + mb) * 512) + fr * 32 + pq8;    // row nh+mb*16+fr, quad q
      bf16x8 ah = *(const bf16x8*)&sAhi[off];
      bf16x8 al = *(const bf16x8*)&sAlo[off];
#pragma unroll
      for (int tb = 0; tb < 4; ++tb) {
        acc[mb][tb] = __builtin_amdgcn_mfma_f32_16x16x32_bf16(ah, bh[tb], acc[mb][tb], 0, 0, 0);
        acc[mb][tb] = __builtin_amdgcn_mfma_f32_16x16x32_bf16(ah, bl[tb], acc[mb][tb], 0, 0, 0);
        acc[mb][tb] = __builtin_amdgcn_mfma_f32_16x16x32_bf16(al, bh[tb], acc[mb][tb], 0, 0, 0);
      }
    }
    __syncthreads();
  }

#pragma unroll
  for (int tb = 0; tb < 4; ++tb) {
    const int tl = th + tb * 16 + fr;
    const int t = t0 + tl;
    float tmp[16];
    float m = -FLT_MAX; int id = 0;
#pragma unroll
    for (int mb = 0; mb < 4; ++mb)
#pragma unroll
      for (int r = 0; r < 4; ++r) {
        float v = acc[mb][tb][r] * SCALE;
        int n = n0 + nh + mb * 16 + q * 4 + r;
        S[((size_t)b * NN + n) * TT + t] = v;
        tmp[mb * 4 + r] = v;
        int nl = nh + mb * 16 + q * 4 + r;
        if (v > m) { m = v; id = nl; }
      }
    float l = 0.f;
#pragma unroll
    for (int j = 0; j < 16; ++j) l += __expf(tmp[j] - m);
#pragma unroll
    for (int off = 16; off <= 32; off <<= 1) {
      float m2 = __shfl_xor(m, off);
      float l2 = __shfl_xor(l, off);
      int i2 = __shfl_xor(id, off);
      if (m2 > m)       { l = l * __expf(m - m2) + l2; m = m2; id = i2; }
      else if (m2 == m) { l += l2; id = min(id, i2); }
      else              { l += l2 * __expf(m2 - m); }
    }
    if (q == 0) {
      int slot = (w & 1) * 128 + tl;
      sm[slot] = m; sl[slot] = l; si[slot] = id;
    }
  }
  __syncthreads();
  if (tid < 128) {
    float m = sm[tid], l = sl[tid]; int id = si[tid];
    float m2 = sm[128 + tid], l2 = sl[128 + tid]; int i2 = si[128 + tid];
    if (m2 > m)       { l = l * __expf(m - m2) + l2; m = m2; id = i2; }
    else if (m2 == m) { l += l2; id = min(id, i2); }
    else              { l += l2 * __expf(m2 - m); }
    size_t p = ((size_t)b * 32 + cy) * TT + t0 + tid;
    mPart[p] = m; lPart[p] = l; iPart[p] = n0 + id;
  }
}

// ---------------- K3: fused stats-final + A=exp(S-m)*rl + Rpart = V @ A ----------------
// NSPLIT=4: grid (32,4,8) = 1024 blocks = 4/CU (TLP hides latency). V staged with
// line-contiguous glds (16 rows x 64B per glds, quad-XOR swizzle); A loaded to regs
// one chunk ahead; counted vmcnt(8) keeps next chunk's staging in flight across barrier.
__global__ __launch_bounds__(256) void gemm_out_fused2(const unsigned short* __restrict__ Vh,
                                                       float* __restrict__ A,   // in: raw S, out: normalized
                                                       const float* __restrict__ mPart,
                                                       const float* __restrict__ lPart,
                                                       const int* __restrict__ iPart,
                                                       float* __restrict__ Rpart,
                                                       float* __restrict__ outMax) {
  __shared__ __align__(16) short sV[2][256 * 32];   // 2 x 16 KB, [wave][group][64 granules]
  __shared__ __align__(16) short sA[32 * 40];       // [t][n] pad 40
  __shared__ float rsm[8][32], rsl[8][32];
  __shared__ int   rsi[8][32];
  __shared__ float sm[32], srl[32];

  // decode with XCD affinity: lin%8 = XCD = batch b
  const int lin = blockIdx.x + (blockIdx.y << 5) + (blockIdx.z << 7);
  const int b  = lin & 7;
  const int ny = (lin >> 3) & 3;
  const int t0 = ((lin >> 5) & 31) * 32;

  const int tid = threadIdx.x;
  const int lane = tid & 63, w = tid >> 6;
  const int fr = lane & 15, q = lane >> 4, fk = q * 8;
  const int sn = tid >> 3, tg = tid & 7;

  const unsigned short* Vb = Vh + (size_t)b * DD * NN;
  float* Ab = A + (size_t)b * NN * TT;
  float* Arow = Ab + (size_t)sn * TT + t0 + tg * 4;

  // staging geometry (wave w owns d-rows w*64..+63): glds c covers rows w*64+c*16..+15.
  const int R = lane >> 2;
  const int Qq = (lane & 3) ^ ((lane >> 3) & 3);
  const unsigned short* vsrc = Vb + (size_t)(w * 64 + R) * NN + Qq * 8;
  const int pq8 = (q ^ ((fr >> 1) & 3)) * 8;
  const int n0 = ny * 1024;

  // prologue: stage chunk 0 + load A(0)
#pragma unroll
  for (int c = 0; c < 4; ++c)
    glds16(vsrc + (size_t)(c * 16) * NN + n0, &sV[0][(w * 4 + c) * 512]);
  float4 cur = *(const float4*)(Arow + (size_t)n0 * TT);

  // stats final (redundant per ny — removes a launch): merge 32 chunk partials per t
  {
    const int tl = tid & 31, g = tid >> 5;
    float m = -FLT_MAX, l = 0.f; int idx = 0;
#pragma unroll
    for (int cc = 0; cc < 4; ++cc) {
      size_t p = ((size_t)b * 32 + g * 4 + cc) * TT + t0 + tl;
      float m2 = mPart[p], l2 = lPart[p]; int i2 = iPart[p];
      if (m2 > m)       { l = l * __expf(m - m2) + l2; m = m2; idx = i2; }
      else if (m2 == m) { l += l2; idx = min(idx, i2); }
      else              { l += l2 * __expf(m2 - m); }
    }
    rsm[g][tl] = m; rsl[g][tl] = l; rsi[g][tl] = idx;
  }
  __syncthreads();
  if (tid < 32) {
    float m = rsm[0][tid], l = rsl[0][tid]; int idx = rsi[0][tid];
#pragma unroll
    for (int g = 1; g < 8; ++g) {
      float m2 = rsm[g][tid], l2 = rsl[g][tid]; int i2 = rsi[g][tid];
      if (m2 > m)       { l = l * __expf(m - m2) + l2; m = m2; idx = i2; }
      else if (m2 == m) { l += l2; idx = min(idx, i2); }
      else              { l += l2 * __expf(m2 - m); }
    }
    sm[tid] = m; srl[tid] = 1.0f / l;
    if (ny == 0) outMax[(size_t)b * TT + t0 + tid] = (float)idx;
  }
  asm volatile("s_waitcnt vmcnt(0)" ::: "memory");   // prologue staging complete
  __syncthreads();

  const float4 mv = *(const float4*)&sm[tg * 4];
  const float4 rv = *(const float4*)&srl[tg * 4];

  f32x4 acc[4][2];
#pragma unroll
  for (int i = 0; i < 4; ++i) { acc[i][0] = (f32x4){0,0,0,0}; acc[i][1] = (f32x4){0,0,0,0}; }

  // 31 steady iters + peeled last. Per-iter VMEM: 4 glds + 1 A-load + 1 A-store.
  // At the wait, ops newer than chunk-t's glds = Aload(t)+store(t-1)+4 glds(t+1)+Aload(t+1)+store(t) = 8.
  for (int it = 0; it < 31; ++it) {
    const int nn = n0 + it * 32;
    const int bi = it & 1;
#pragma unroll
    for (int c = 0; c < 4; ++c)
      glds16(vsrc + (size_t)(c * 16) * NN + (nn + 32), &sV[bi ^ 1][(w * 4 + c) * 512]);
    float4 nxt = *(const float4*)(Arow + (size_t)(nn + 32) * TT);

    float4 av;
    av.x = __expf(cur.x - mv.x) * rv.x;
    av.y = __expf(cur.y - mv.y) * rv.y;
    av.z = __expf(cur.z - mv.z) * rv.z;
    av.w = __expf(cur.w - mv.w) * rv.w;
    *(float4*)(Arow + (size_t)nn * TT) = av;
    sA[(tg * 4 + 0) * 40 + sn] = (short)f2bf(av.x);
    sA[(tg * 4 + 1) * 40 + sn] = (short)f2bf(av.y);
    sA[(tg * 4 + 2) * 40 + sn] = (short)f2bf(av.z);
    sA[(tg * 4 + 3) * 40 + sn] = (short)f2bf(av.w);

    __builtin_amdgcn_sched_barrier(0);
    asm volatile("s_waitcnt vmcnt(8) lgkmcnt(0)" ::: "memory");
    wg_barrier();                                    // sA/sV(t) ready

    bf16x8 bf0 = *(const bf16x8*)&sA[(0 * 16 + fr) * 40 + fk];
    bf16x8 bf1 = *(const bf16x8*)&sA[(1 * 16 + fr) * 40 + fk];
#pragma unroll
    for (int mb = 0; mb < 4; ++mb) {
      bf16x8 af = *(const bf16x8*)&sV[bi][w * 2048 + mb * 512 + fr * 32 + pq8];
      acc[mb][0] = __builtin_amdgcn_mfma_f32_16x16x32_bf16(af, bf0, acc[mb][0], 0, 0, 0);
      acc[mb][1] = __builtin_amdgcn_mfma_f32_16x16x32_bf16(af, bf1, acc[mb][1], 0, 0, 0);
    }
    wg_barrier();                                    // sA reads done before next write
    cur = nxt;
  }

  { // peeled last chunk (it=31, buffer 1)
    const int nn = n0 + 992;
    float4 av;
    av.x = __expf(cur.x - mv.x) * rv.x;
    av.y = __expf(cur.y - mv.y) * rv.y;
    av.z = __expf(cur.z - mv.z) * rv.z;
    av.w = __expf(cur.w - mv.w) * rv.w;
    *(float4*)(Arow + (size_t)nn * TT) = av;
    sA[(tg * 4 + 0) * 40 + sn] = (short)f2bf(av.x);
    sA[(tg * 4 + 1) * 40 + sn] = (short)f2bf(av.y);
    sA[(tg * 4 + 2) * 40 + sn] = (short)f2bf(av.z);
    sA[(tg * 4 + 3) * 40 + sn] = (short)f2bf(av.w);

    __builtin_amdgcn_sched_barrier(0);
    asm volatile("s_waitcnt vmcnt(0) lgkmcnt(0)" ::: "memory");
    wg_barrier();

    bf16x8 bf0 = *(const bf16x8*)&sA[(0 * 16 + fr) * 40 + fk];
    bf16x8 bf1 = *(const bf16x8*)&sA[(1 * 16 + fr) * 40 + fk];
#pragma unroll
    for (int mb = 0; mb < 4; ++mb) {
      bf16x8 af = *(const bf16x8*)&sV[1][w * 2048 + mb * 512 + fr * 32 + pq8];
      acc[mb][0] = __builtin_amdgcn_mfma_f32_16x16x32_bf16(af, bf0, acc[mb][0], 0, 0, 0);
      acc[mb][1] = __builtin_amdgcn_mfma_f32_16x16x32_bf16(af, bf1, acc[mb][1], 0, 0, 0);
    }
  }

  // epilogue: partial R for this ny
#pragma unroll
  for (int mb = 0; mb < 4; ++mb)
#pragma unroll
    for (int tb = 0; tb < 2; ++tb) {
      const int t = t0 + tb * 16 + fr;
#pragma unroll
      for (int r = 0; r < 4; ++r) {
        const int d = w * 64 + mb * 16 + q * 4 + r;
        Rpart[(((size_t)b * 4 + ny) * DD + d) * TT + t] = acc[mb][tb][r];
      }
    }
}

// ---------------- K4: R_ top = sum of 4 R partials; bottom = Q copy ----------------
__global__ __launch_bounds__(256) void combine(const float* __restrict__ Rpart,
                                               const float* __restrict__ Qp,
                                               float* __restrict__ out) {
  int g = blockIdx.x * 256 + threadIdx.x;
  int e = g * 4;
  int t = e & 1023;
  int row = e >> 10;
  int d = row & 511, b = row >> 9;
  if (d < 256) {
    float4 s0 = *(const float4*)(Rpart + (((size_t)b * 4 + 0) * DD + d) * TT + t);
    float4 s1 = *(const float4*)(Rpart + (((size_t)b * 4 + 1) * DD + d) * TT + t);
    float4 s2 = *(const float4*)(Rpart + (((size_t)b * 4 + 2) * DD + d) * TT + t);
    float4 s3 = *(const float4*)(Rpart + (((size_t)b * 4 + 3) * DD + d) * TT + t);
    float4 r = make_float4(s0.x + s1.x + s2.x + s3.x, s0.y + s1.y + s2.y + s3.y,
                           s0.z + s1.z + s2.z + s3.z, s0.w + s1.w + s2.w + s3.w);
    *(float4*)(out + ((size_t)b * 512 + d) * TT + t) = r;
  } else {
    float4 v = *(const float4*)(Qp + ((size_t)b * 256 + (d - 256)) * TT + t);
    *(float4*)(out + ((size_t)b * 512 + d) * TT + t) = v;
  }
}

// =================== fp32 fallback path (ws too small) ===================
__global__ __launch_bounds__(256) void gemm_scores_fp32(const float* __restrict__ Kp,
                                                        const float* __restrict__ Qp,
                                                        float* __restrict__ S) {
  const int b = blockIdx.z;
  const int n0 = blockIdx.y * 128;
  const int t0 = blockIdx.x * 128;
  const int tid = threadIdx.x;
  const int tx = tid & 15, ty = tid >> 4;
  __shared__ float Kt[8][128];
  __shared__ float Qt[8][128];
  float acc[8][8];
#pragma unroll
  for (int i = 0; i < 8; ++i)
#pragma unroll
    for (int j = 0; j < 8; ++j) acc[i][j] = 0.f;
  const int lin = tid * 4;
  const int lkk = lin >> 7, lcol = lin & 127;
  const float* Kbase = Kp + (size_t)b * DD * NN;
  const float* Qbase = Qp + (size_t)b * DD * TT;
  for (int dd0 = 0; dd0 < DD; dd0 += 8) {
    float4 kv = *(const float4*)(Kbase + (size_t)(dd0 + lkk) * NN + n0 + lcol);
    float4 qv = *(const float4*)(Qbase + (size_t)(dd0 + lkk) * TT + t0 + lcol);
    __syncthreads();
    *(float4*)&Kt[lkk][lcol] = kv;
    *(float4*)&Qt[lkk][lcol] = qv;
    __syncthreads();
#pragma unroll
    for (int kk = 0; kk < 8; ++kk) {
      float4 a0 = *(float4*)&Kt[kk][ty * 4];
      float4 a1 = *(float4*)&Kt[kk][64 + ty * 4];
      float4 b0 = *(float4*)&Qt[kk][tx * 4];
      float4 b1 = *(float4*)&Qt[kk][64 + tx * 4];
      float av[8] = {a0.x, a0.y, a0.z, a0.w, a1.x, a1.y, a1.z, a1.w};
      float bv[8] = {b0.x, b0.y, b0.z, b0.w, b1.x, b1.y, b1.z, b1.w};
#pragma unroll
      for (int i = 0; i < 8; ++i)
#pragma unroll
        for (int j = 0; j < 8; ++j) acc[i][j] += av[i] * bv[j];
    }
  }
#pragma unroll
  for (int i = 0; i < 8; ++i) {
    int r = n0 + ((i < 4) ? (ty * 4 + i) : (64 + ty * 4 + i - 4));
    float* dst = S + ((size_t)b * NN + r) * TT + t0;
    *(float4*)(dst + tx * 4) = make_float4(acc[i][0] * SCALE, acc[i][1] * SCALE, acc[i][2] * SCALE, acc[i][3] * SCALE);
    *(float4*)(dst + 64 + tx * 4) = make_float4(acc[i][4] * SCALE, acc[i][5] * SCALE, acc[i][6] * SCALE, acc[i][7] * SCALE);
  }
}

__global__ __launch_bounds__(256) void stats_partial_fb(const float* __restrict__ S,
                                                        float* __restrict__ mPart,
                                                        float* __restrict__ lPart,
                                                        int* __restrict__ iPart) {
  const int tid = threadIdx.x;
  const int tx = tid & 63, ty = tid >> 6;
  const int b = blockIdx.z;
  const int t = blockIdx.x * 64 + tx;
  const int nbase = blockIdx.y * 512;
  float m = -FLT_MAX, l = 0.f;
  int idx = 0;
  const float* col = S + (size_t)b * NN * TT + t;
  for (int n = nbase + ty; n < nbase + 512; n += 4) {
    float s = col[(size_t)n * TT];
    if (s > m) { l = l * __expf(m - s) + 1.0f; m = s; idx = n; }
    else        l += __expf(s - m);
  }
  __shared__ float sm[4][64], sl[4][64];
  __shared__ int si[4][64];
  sm[ty][tx] = m; sl[ty][tx] = l; si[ty][tx] = idx;
  __syncthreads();
  if (ty == 0) {
#pragma unroll
    for (int k = 1; k < 4; ++k) {
      float m2 = sm[k][tx], l2 = sl[k][tx];
      int i2 = si[k][tx];
      if (m2 > m)       { l = l * __expf(m - m2) + l2; m = m2; idx = i2; }
      else if (m2 == m) { l += l2; idx = min(idx, i2); }
      else              { l += l2 * __expf(m2 - m); }
    }
    size_t p = (size_t)(b * 8 + blockIdx.y) * TT + t;
    mPart[p] = m; lPart[p] = l; iPart[p] = idx;
  }
}

__global__ __launch_bounds__(256) void stats_final_fb(const float* __restrict__ mPart,
                                                      const float* __restrict__ lPart,
                                                      const int* __restrict__ iPart,
                                                      float* __restrict__ mArr,
                                                      float* __restrict__ rlArr,
                                                      float* __restrict__ outMax) {
  int col = blockIdx.x * 256 + threadIdx.x;
  int b = col >> 10, t = col & 1023;
  float m = -FLT_MAX, l = 0.f;
  int idx = 0;
#pragma unroll
  for (int c = 0; c < 8; ++c) {
    size_t p = (size_t)(b * 8 + c) * TT + t;
    float m2 = mPart[p], l2 = lPart[p];
    int i2 = iPart[p];
    if (m2 > m)       { l = l * __expf(m - m2) + l2; m = m2; idx = i2; }
    else if (m2 == m) { l += l2; idx = min(idx, i2); }
    else              { l += l2 * __expf(m2 - m); }
  }
  mArr[col] = m;
  rlArr[col] = 1.0f / l;
  outMax[col] = (float)idx;
}

__global__ __launch_bounds__(256) void normalize_fb(float* __restrict__ A,
                                                    const float* __restrict__ mArr,
                                                    const float* __restrict__ rlArr) {
  int g = blockIdx.x * 256 + threadIdx.x;
  float4 s = ((const float4*)A)[g];
  int e = g * 4;
  int t0 = e & 1023;
  int row = e >> 10;
  int b = row >> 12;
  int cb = (b << 10) + t0;
  float4 r;
  r.x = __expf(s.x - mArr[cb + 0]) * rlArr[cb + 0];
  r.y = __expf(s.y - mArr[cb + 1]) * rlArr[cb + 1];
  r.z = __expf(s.z - mArr[cb + 2]) * rlArr[cb + 2];
  r.w = __expf(s.w - mArr[cb + 3]) * rlArr[cb + 3];
  ((float4*)A)[g] = r;
}

__global__ __launch_bounds__(256) void gemm_out_fp32(const float* __restrict__ Vp,
                                                     const float* __restrict__ A,
                                                     float* __restrict__ Rout) {
  const int b = blockIdx.z;
  const int m0 = blockIdx.y * 64;
  const int t0 = blockIdx.x * 128;
  const int tid = threadIdx.x;
  const int tx = tid & 15, ty = tid >> 4;
  __shared__ float Vt[16][68];
  __shared__ float At[16][128];
  float acc[4][8];
#pragma unroll
  for (int i = 0; i < 4; ++i)
#pragma unroll
    for (int j = 0; j < 8; ++j) acc[i][j] = 0.f;
  const float* Vbase = Vp + (size_t)b * DD * NN;
  const float* Abase = A + (size_t)b * NN * TT;
  const int vmm = tid >> 2, vkk = (tid & 3) * 4;
  const int akk = tid >> 5, att = (tid * 4) & 127;
  for (int nn0 = 0; nn0 < NN; nn0 += 16) {
    float4 vv = *(const float4*)(Vbase + (size_t)(m0 + vmm) * NN + nn0 + vkk);
    float4 a0 = *(const float4*)(Abase + (size_t)(nn0 + akk) * TT + t0 + att);
    float4 a1 = *(const float4*)(Abase + (size_t)(nn0 + akk + 8) * TT + t0 + att);
    __syncthreads();
    Vt[vkk + 0][vmm] = vv.x; Vt[vkk + 1][vmm] = vv.y;
    Vt[vkk + 2][vmm] = vv.z; Vt[vkk + 3][vmm] = vv.w;
    *(float4*)&At[akk][att] = a0;
    *(float4*)&At[akk + 8][att] = a1;
    __syncthreads();
#pragma unroll
    for (int kk = 0; kk < 16; ++kk) {
      float4 a4 = *(float4*)&Vt[kk][ty * 4];
      float4 b0 = *(float4*)&At[kk][tx * 4];
      float4 b1 = *(float4*)&At[kk][64 + tx * 4];
      float av[4] = {a4.x, a4.y, a4.z, a4.w};
      float bv[8] = {b0.x, b0.y, b0.z, b0.w, b1.x, b1.y, b1.z, b1.w};
#pragma unroll
      for (int i = 0; i < 4; ++i)
#pragma unroll
        for (int j = 0; j < 8; ++j) acc[i][j] += av[i] * bv[j];
    }
  }
#pragma unroll
  for (int i = 0; i < 4; ++i) {
    int r = m0 + ty * 4 + i;
    float* dst = Rout + (size_t)b * (2 * DD) * TT + (size_t)r * TT + t0;
    *(float4*)(dst + tx * 4) = make_float4(acc[i][0], acc[i][1], acc[i][2], acc[i][3]);
    *(float4*)(dst + 64 + tx * 4) = make_float4(acc[i][4], acc[i][5], acc[i][6], acc[i][7]);
  }
}

__global__ __launch_bounds__(256) void qcopy(const float* __restrict__ Qp,
                                             float* __restrict__ out) {
  int g = blockIdx.x * 256 + threadIdx.x;
  int e = g * 4;
  int t0 = e & 1023;
  int row = e >> 10;
  int dd = row & 255, b = row >> 8;
  float4 v = ((const float4*)Qp)[g];
  *(float4*)(out + (size_t)b * 512 * TT + (size_t)(256 + dd) * TT + t0) = v;
}

extern "C" void kernel_launch(void* const* d_in, const int* in_sizes, int n_in,
                              void* d_out, int out_size, void* d_ws, size_t ws_size,
                              hipStream_t stream) {
  const float* Kp = (const float*)d_in[0];
  const float* Vp = (const float*)d_in[1];
  const float* Qp = (const float*)d_in[2];
  float* out = (float*)d_out;
  float* R_ = out;
  float* A = out + 4194304;
  float* outMax = out + 4194304 + 33554432;

  char* wsb = (char*)d_ws;
  float* mPart = (float*)(wsb + MPART_OFF);
  float* lPart = (float*)(wsb + LPART_OFF);
  int*   iPart = (int*)(wsb + IPART_OFF);
  float* mArr  = (float*)(wsb + MARR_OFF);
  float* rlArr = (float*)(wsb + RLARR_OFF);

  const bool fast = (ws_size >= WS_NEED);

  if (fast) {
    unsigned short* KtHi = (unsigned short*)(wsb + KT_HI_OFF);
    unsigned short* KtLo = (unsigned short*)(wsb + KT_LO_OFF);
    unsigned short* QtHi = (unsigned short*)(wsb + QT_HI_OFF);
    unsigned short* QtLo = (unsigned short*)(wsb + QT_LO_OFF);
    unsigned short* Vh   = (unsigned short*)(wsb + VH_OFF);
    float* Rpart = (float*)(wsb + RPART_OFF);   // aliases Kt (dead after gemm_scores)

    convert_t2<<<dim3(80, 4, BB), 256, 0, stream>>>(Kp, Qp, KtHi, KtLo, QtHi, QtLo);
    convert_v<<<dim3((BB * DD * NN / 4) / 256), 256, 0, stream>>>(Vp, Vh);
    gemm_scores_mfma<<<dim3(TT / 128, NN / 128, BB), 256, 0, stream>>>(
        KtHi, KtLo, QtHi, QtLo, A, mPart, lPart, iPart);
    gemm_out_fused2<<<dim3(TT / 32, 4, BB), 256, 0, stream>>>(
        Vh, A, mPart, lPart, iPart, Rpart, outMax);
    combine<<<dim3((BB * 512 * TT / 4) / 256), 256, 0, stream>>>(Rpart, Qp, R_);
  } else {
    gemm_scores_fp32<<<dim3(TT / 128, NN / 128, BB), 256, 0, stream>>>(Kp, Qp, A);
    stats_partial_fb<<<dim3(TT / 64, NN / 512, BB), 256, 0, stream>>>(A, mPart, lPart, iPart);
    stats_final_fb<<<dim3(32), 256, 0, stream>>>(mPart, lPart, iPart, mArr, rlArr, outMax);
    normalize_fb<<<dim3((BB * NN * TT / 4) / 256), 256, 0, stream>>>(A, mArr, rlArr);
    gemm_out_fp32<<<dim3(TT / 128, DD / 64, BB), 256, 0, stream>>>(Vp, A, R_);
    qcopy<<<dim3((BB * DD * TT / 4) / 256), 256, 0, stream>>>(Qp, R_);
  }
}

// Round 6
// 328.404 us; speedup vs baseline: 1.3403x; 1.0178x over previous
//
#include <hip/hip_runtime.h>
#include <cfloat>

#define BB 8
#define DD 256
#define NN 4096
#define TT 1024
constexpr float SCALE = 0.0625f;   // 1/sqrt(256)

typedef __attribute__((ext_vector_type(8))) short bf16x8;
typedef __attribute__((ext_vector_type(4))) float f32x4;
typedef __attribute__((ext_vector_type(8))) unsigned short u16x8;

__device__ inline unsigned short f2bf(float x) {
  union { float f; unsigned u; } v; v.f = x;
  unsigned r = v.u + 0x7fff + ((v.u >> 16) & 1);
  return (unsigned short)(r >> 16);
}
__device__ inline float bf2f(unsigned short h) {
  union { unsigned u; float f; } v; v.u = ((unsigned)h) << 16;
  return v.f;
}

__device__ inline void glds16(const unsigned short* g, const short* lbase) {
  __builtin_amdgcn_global_load_lds((const __attribute__((address_space(1))) unsigned int*)g,
                                   (__attribute__((address_space(3))) unsigned int*)lbase,
                                   16, 0, 0);
}

// raw barrier bracketed by scheduler fences
__device__ inline void wg_barrier() {
  __builtin_amdgcn_sched_barrier(0);
  __builtin_amdgcn_s_barrier();
  __builtin_amdgcn_sched_barrier(0);
}

// ---- ws layout (bytes) ----
#define MPART_OFF 0u                      // 8*32*1024 f = 1 MB
#define LPART_OFF (1u << 20)
#define IPART_OFF (2u << 20)
#define MARR_OFF  (3u << 20)
#define RLARR_OFF ((3u << 20) + 32768u)
#define CONV_OFF  (4u << 20)
#define KT_HI_OFF (CONV_OFF)
#define KT_LO_OFF (CONV_OFF + 16777216u)
#define QT_HI_OFF (CONV_OFF + 33554432u)
#define QT_LO_OFF (CONV_OFF + 37748736u)
#define VH_OFF    (CONV_OFF + 41943040u)
#define RPART_OFF (CONV_OFF)              // aliases Kt hi/lo (dead after gemm_scores)
#define WS_NEED   (62914560ull)

// ---------------- convert: K/Q transpose+split, V cast — one launch ----------------
// bx<64: K-transpose; 64<=bx<80: Q-transpose; bx>=80: V elementwise cast.
__global__ __launch_bounds__(256) void convert_all(const float* __restrict__ Ksrc,
                                                   const float* __restrict__ Qsrc,
                                                   const float* __restrict__ Vsrc,
                                                   unsigned short* __restrict__ KHi,
                                                   unsigned short* __restrict__ KLo,
                                                   unsigned short* __restrict__ QHi,
                                                   unsigned short* __restrict__ QLo,
                                                   unsigned short* __restrict__ Vh) {
  __shared__ float tile[64][65];
  const int bx = blockIdx.x;
  const int b = blockIdx.z;
  const int tid = threadIdx.x;

  if (bx >= 80) {   // ---- V cast: 1 float4 per thread ----
    const int y = blockIdx.y;
    size_t g = (((size_t)b * 4 + y) * 256 + (bx - 80)) * 256 + tid;
    float4 v = ((const float4*)Vsrc)[g];
    unsigned short h[4] = {f2bf(v.x), f2bf(v.y), f2bf(v.z), f2bf(v.w)};
    *(ushort4*)(Vh + g * 4) = *(ushort4*)h;
    return;
  }

  const int d0 = blockIdx.y * 64;
  const float* src; unsigned short* dhi; unsigned short* dlo; int C; int c0;
  if (bx < 64) { src = Ksrc; dhi = KHi; dlo = KLo; C = NN; c0 = bx * 64; }
  else         { src = Qsrc; dhi = QHi; dlo = QLo; C = TT; c0 = (bx - 64) * 64; }
  const float* s = src + ((size_t)b * DD + d0) * C + c0;
  const int r = tid >> 4, cg = (tid & 15) * 4;
#pragma unroll
  for (int it = 0; it < 4; ++it) {
    float4 v = *(const float4*)(s + (size_t)(r + it * 16) * C + cg);
    tile[r + it * 16][cg + 0] = v.x; tile[r + it * 16][cg + 1] = v.y;
    tile[r + it * 16][cg + 2] = v.z; tile[r + it * 16][cg + 3] = v.w;
  }
  __syncthreads();
  const int cl = tid >> 2, dg = (tid & 3) * 16;
  unsigned short hi[16], lo[16];
#pragma unroll
  for (int j = 0; j < 16; ++j) {
    float x = tile[dg + j][cl];
    unsigned short h = f2bf(x);
    hi[j] = h;
    lo[j] = f2bf(x - bf2f(h));
  }
  size_t off = ((size_t)b * C + c0 + cl) * DD + d0 + dg;
  *(u16x8*)(dhi + off) = *(u16x8*)&hi[0];
  *(u16x8*)(dhi + off + 8) = *(u16x8*)&hi[8];
  *(u16x8*)(dlo + off) = *(u16x8*)&lo[0];
  *(u16x8*)(dlo + off + 8) = *(u16x8*)&lo[8];
}

// ---------------- K1: S = scale*K^T Q (split-bf16 MFMA) + per-block softmax stats ----------------
// Line-contiguous glds staging (16 rows x 64B per glds, quad-XOR swizzle) + LDS double
// buffer: stage chunk k+1 while computing chunk k, counted vmcnt(8) across the barrier.
__global__ __launch_bounds__(256) void gemm_scores_mfma(const unsigned short* __restrict__ KtHi,
                                                        const unsigned short* __restrict__ KtLo,
                                                        const unsigned short* __restrict__ QtHi,
                                                        const unsigned short* __restrict__ QtLo,
                                                        float* __restrict__ S,
                                                        float* __restrict__ mPart,
                                                        float* __restrict__ lPart,
                                                        int* __restrict__ iPart) {
  __shared__ __align__(16) short sAhi[2][128 * 32];
  __shared__ __align__(16) short sAlo[2][128 * 32];
  __shared__ __align__(16) short sBhi[2][128 * 32];
  __shared__ __align__(16) short sBlo[2][128 * 32];
  __shared__ float sm[256], sl[256];
  __shared__ int si[256];

  // bijective XCD swizzle: 2048 blocks, XCD k handles batch k
  const int lin = blockIdx.x + ((blockIdx.y + (blockIdx.z << 5)) << 3);
  const int wg = ((lin & 7) << 8) + (lin >> 3);
  const int b = wg >> 8;
  const int cy = (wg >> 3) & 31;
  const int n0 = cy * 128;
  const int t0 = (wg & 7) * 128;
  const int tid = threadIdx.x;
  const int lane = tid & 63, w = tid >> 6;
  const int nh = (w & 1) * 64, th = (w >> 1) * 64;
  const int fr = lane & 15, q = lane >> 4;

  const unsigned short* aHi = KtHi + ((size_t)b * NN + n0) * DD;
  const unsigned short* aLo = KtLo + ((size_t)b * NN + n0) * DD;
  const unsigned short* bHi = QtHi + ((size_t)b * TT + t0) * DD;
  const unsigned short* bLo = QtLo + ((size_t)b * TT + t0) * DD;

  f32x4 acc[4][4];
#pragma unroll
  for (int i = 0; i < 4; ++i)
#pragma unroll
    for (int j = 0; j < 4; ++j) acc[i][j] = (f32x4){0.f, 0.f, 0.f, 0.f};

  // staging geometry: group g = w*2+c covers rows g*16..+15; lane: row-in-group R = l>>2,
  // stored pos P = l&3 holds quad Q = P ^ ((R>>1)&3). 4 consecutive lanes = one 64B line.
  const int Rr = lane >> 2;
  const int Qq = (lane & 3) ^ ((lane >> 3) & 3);
  const size_t s0 = (size_t)((w * 2 + 0) * 16 + Rr) * DD + Qq * 8;
  const size_t s1 = (size_t)((w * 2 + 1) * 16 + Rr) * DD + Qq * 8;
  const int g0 = (w * 2 + 0) * 512;   // shorts (1KB per group)
  const int g1 = (w * 2 + 1) * 512;
  const int pq8 = (q ^ ((fr >> 1) & 3)) * 8;   // read-side pos for quad q at row fr

#define STAGE_K1(buf, kk)                         \
    glds16(aHi + s0 + (kk), &sAhi[buf][g0]);      \
    glds16(aHi + s1 + (kk), &sAhi[buf][g1]);      \
    glds16(aLo + s0 + (kk), &sAlo[buf][g0]);      \
    glds16(aLo + s1 + (kk), &sAlo[buf][g1]);      \
    glds16(bHi + s0 + (kk), &sBhi[buf][g0]);      \
    glds16(bHi + s1 + (kk), &sBhi[buf][g1]);      \
    glds16(bLo + s0 + (kk), &sBlo[buf][g0]);      \
    glds16(bLo + s1 + (kk), &sBlo[buf][g1]);

  STAGE_K1(0, 0);

  for (int step = 0; step < 8; ++step) {
    const int bi = step & 1;
    if (step < 7) {
      STAGE_K1(bi ^ 1, (step + 1) * 32);
      __builtin_amdgcn_sched_barrier(0);
      asm volatile("s_waitcnt vmcnt(8)" ::: "memory");   // buf bi's 8 glds done; next 8 in flight
    } else {
      __builtin_amdgcn_sched_barrier(0);
      asm volatile("s_waitcnt vmcnt(0)" ::: "memory");
    }
    wg_barrier();                                        // buf bi visible to all waves

    bf16x8 bh[4], bl[4];
#pragma unroll
    for (int tb = 0; tb < 4; ++tb) {
      int off = (((w >> 1) * 4 + tb) * 512) + fr * 32 + pq8;   // row th+tb*16+fr, quad q
      bh[tb] = *(const bf16x8*)&sBhi[bi][off];
      bl[tb] = *(const bf16x8*)&sBlo[bi][off];
    }
#pragma unroll
    for (int mb = 0; mb < 4; ++mb) {
      int off = (((w & 1) * 4 + mb) * 512) + fr * 32 + pq8;    // row nh+mb*16+fr, quad q
      bf16x8 ah = *(const bf16x8*)&sAhi[bi][off];
      bf16x8 al = *(const bf16x8*)&sAlo[bi][off];
#pragma unroll
      for (int tb = 0; tb < 4; ++tb) {
        acc[mb][tb] = __builtin_amdgcn_mfma_f32_16x16x32_bf16(ah, bh[tb], acc[mb][tb], 0, 0, 0);
        acc[mb][tb] = __builtin_amdgcn_mfma_f32_16x16x32_bf16(ah, bl[tb], acc[mb][tb], 0, 0, 0);
        acc[mb][tb] = __builtin_amdgcn_mfma_f32_16x16x32_bf16(al, bh[tb], acc[mb][tb], 0, 0, 0);
      }
    }
    wg_barrier();                                        // reads done before buf bi is re-staged
  }
#undef STAGE_K1

#pragma unroll
  for (int tb = 0; tb < 4; ++tb) {
    const int tl = th + tb * 16 + fr;
    const int t = t0 + tl;
    float tmp[16];
    float m = -FLT_MAX; int id = 0;
#pragma unroll
    for (int mb = 0; mb < 4; ++mb)
#pragma unroll
      for (int r = 0; r < 4; ++r) {
        float v = acc[mb][tb][r] * SCALE;
        int n = n0 + nh + mb * 16 + q * 4 + r;
        S[((size_t)b * NN + n) * TT + t] = v;
        tmp[mb * 4 + r] = v;
        int nl = nh + mb * 16 + q * 4 + r;
        if (v > m) { m = v; id = nl; }
      }
    float l = 0.f;
#pragma unroll
    for (int j = 0; j < 16; ++j) l += __expf(tmp[j] - m);
#pragma unroll
    for (int off = 16; off <= 32; off <<= 1) {
      float m2 = __shfl_xor(m, off);
      float l2 = __shfl_xor(l, off);
      int i2 = __shfl_xor(id, off);
      if (m2 > m)       { l = l * __expf(m - m2) + l2; m = m2; id = i2; }
      else if (m2 == m) { l += l2; id = min(id, i2); }
      else              { l += l2 * __expf(m2 - m); }
    }
    if (q == 0) {
      int slot = (w & 1) * 128 + tl;
      sm[slot] = m; sl[slot] = l; si[slot] = id;
    }
  }
  __syncthreads();
  if (tid < 128) {
    float m = sm[tid], l = sl[tid]; int id = si[tid];
    float m2 = sm[128 + tid], l2 = sl[128 + tid]; int i2 = si[128 + tid];
    if (m2 > m)       { l = l * __expf(m - m2) + l2; m = m2; id = i2; }
    else if (m2 == m) { l += l2; id = min(id, i2); }
    else              { l += l2 * __expf(m2 - m); }
    size_t p = ((size_t)b * 32 + cy) * TT + t0 + tid;
    mPart[p] = m; lPart[p] = l; iPart[p] = n0 + id;
  }
}

// ---------------- K3: fused stats-final + A=exp(S-m)*rl + Rpart = V @ A ----------------
// NSPLIT=4: grid (32,4,8) = 1024 blocks = 4/CU. V staged with line-contiguous glds;
// A loaded to regs one chunk ahead; counted vmcnt(8) across the barrier. (unchanged)
__global__ __launch_bounds__(256) void gemm_out_fused2(const unsigned short* __restrict__ Vh,
                                                       float* __restrict__ A,   // in: raw S, out: normalized
                                                       const float* __restrict__ mPart,
                                                       const float* __restrict__ lPart,
                                                       const int* __restrict__ iPart,
                                                       float* __restrict__ Rpart,
                                                       float* __restrict__ outMax) {
  __shared__ __align__(16) short sV[2][256 * 32];   // 2 x 16 KB
  __shared__ __align__(16) short sA[32 * 40];       // [t][n] pad 40
  __shared__ float rsm[8][32], rsl[8][32];
  __shared__ int   rsi[8][32];
  __shared__ float sm[32], srl[32];

  // decode with XCD affinity: lin%8 = XCD = batch b
  const int lin = blockIdx.x + (blockIdx.y << 5) + (blockIdx.z << 7);
  const int b  = lin & 7;
  const int ny = (lin >> 3) & 3;
  const int t0 = ((lin >> 5) & 31) * 32;

  const int tid = threadIdx.x;
  const int lane = tid & 63, w = tid >> 6;
  const int fr = lane & 15, q = lane >> 4, fk = q * 8;
  const int sn = tid >> 3, tg = tid & 7;

  const unsigned short* Vb = Vh + (size_t)b * DD * NN;
  float* Ab = A + (size_t)b * NN * TT;
  float* Arow = Ab + (size_t)sn * TT + t0 + tg * 4;

  const int Rr = lane >> 2;
  const int Qq = (lane & 3) ^ ((lane >> 3) & 3);
  const unsigned short* vsrc = Vb + (size_t)(w * 64 + Rr) * NN + Qq * 8;
  const int pq8 = (q ^ ((fr >> 1) & 3)) * 8;
  const int n0 = ny * 1024;

  // prologue: stage chunk 0 + load A(0)
#pragma unroll
  for (int c = 0; c < 4; ++c)
    glds16(vsrc + (size_t)(c * 16) * NN + n0, &sV[0][(w * 4 + c) * 512]);
  float4 cur = *(const float4*)(Arow + (size_t)n0 * TT);

  // stats final (redundant per ny): merge 32 chunk partials per t
  {
    const int tl = tid & 31, g = tid >> 5;
    float m = -FLT_MAX, l = 0.f; int idx = 0;
#pragma unroll
    for (int cc = 0; cc < 4; ++cc) {
      size_t p = ((size_t)b * 32 + g * 4 + cc) * TT + t0 + tl;
      float m2 = mPart[p], l2 = lPart[p]; int i2 = iPart[p];
      if (m2 > m)       { l = l * __expf(m - m2) + l2; m = m2; idx = i2; }
      else if (m2 == m) { l += l2; idx = min(idx, i2); }
      else              { l += l2 * __expf(m2 - m); }
    }
    rsm[g][tl] = m; rsl[g][tl] = l; rsi[g][tl] = idx;
  }
  __syncthreads();
  if (tid < 32) {
    float m = rsm[0][tid], l = rsl[0][tid]; int idx = rsi[0][tid];
#pragma unroll
    for (int g = 1; g < 8; ++g) {
      float m2 = rsm[g][tid], l2 = rsl[g][tid]; int i2 = rsi[g][tid];
      if (m2 > m)       { l = l * __expf(m - m2) + l2; m = m2; idx = i2; }
      else if (m2 == m) { l += l2; idx = min(idx, i2); }
      else              { l += l2 * __expf(m2 - m); }
    }
    sm[tid] = m; srl[tid] = 1.0f / l;
    if (ny == 0) outMax[(size_t)b * TT + t0 + tid] = (float)idx;
  }
  asm volatile("s_waitcnt vmcnt(0)" ::: "memory");   // prologue staging complete
  __syncthreads();

  const float4 mv = *(const float4*)&sm[tg * 4];
  const float4 rv = *(const float4*)&srl[tg * 4];

  f32x4 acc[4][2];
#pragma unroll
  for (int i = 0; i < 4; ++i) { acc[i][0] = (f32x4){0,0,0,0}; acc[i][1] = (f32x4){0,0,0,0}; }

  for (int it = 0; it < 31; ++it) {
    const int nn = n0 + it * 32;
    const int bi = it & 1;
#pragma unroll
    for (int c = 0; c < 4; ++c)
      glds16(vsrc + (size_t)(c * 16) * NN + (nn + 32), &sV[bi ^ 1][(w * 4 + c) * 512]);
    float4 nxt = *(const float4*)(Arow + (size_t)(nn + 32) * TT);

    float4 av;
    av.x = __expf(cur.x - mv.x) * rv.x;
    av.y = __expf(cur.y - mv.y) * rv.y;
    av.z = __expf(cur.z - mv.z) * rv.z;
    av.w = __expf(cur.w - mv.w) * rv.w;
    *(float4*)(Arow + (size_t)nn * TT) = av;
    sA[(tg * 4 + 0) * 40 + sn] = (short)f2bf(av.x);
    sA[(tg * 4 + 1) * 40 + sn] = (short)f2bf(av.y);
    sA[(tg * 4 + 2) * 40 + sn] = (short)f2bf(av.z);
    sA[(tg * 4 + 3) * 40 + sn] = (short)f2bf(av.w);

    __builtin_amdgcn_sched_barrier(0);
    asm volatile("s_waitcnt vmcnt(8) lgkmcnt(0)" ::: "memory");
    wg_barrier();                                    // sA/sV(t) ready

    bf16x8 bf0 = *(const bf16x8*)&sA[(0 * 16 + fr) * 40 + fk];
    bf16x8 bf1 = *(const bf16x8*)&sA[(1 * 16 + fr) * 40 + fk];
#pragma unroll
    for (int mb = 0; mb < 4; ++mb) {
      bf16x8 af = *(const bf16x8*)&sV[bi][w * 2048 + mb * 512 + fr * 32 + pq8];
      acc[mb][0] = __builtin_amdgcn_mfma_f32_16x16x32_bf16(af, bf0, acc[mb][0], 0, 0, 0);
      acc[mb][1] = __builtin_amdgcn_mfma_f32_16x16x32_bf16(af, bf1, acc[mb][1], 0, 0, 0);
    }
    wg_barrier();                                    // sA reads done before next write
    cur = nxt;
  }

  { // peeled last chunk (it=31, buffer 1)
    const int nn = n0 + 992;
    float4 av;
    av.x = __expf(cur.x - mv.x) * rv.x;
    av.y = __expf(cur.y - mv.y) * rv.y;
    av.z = __expf(cur.z - mv.z) * rv.z;
    av.w = __expf(cur.w - mv.w) * rv.w;
    *(float4*)(Arow + (size_t)nn * TT) = av;
    sA[(tg * 4 + 0) * 40 + sn] = (short)f2bf(av.x);
    sA[(tg * 4 + 1) * 40 + sn] = (short)f2bf(av.y);
    sA[(tg * 4 + 2) * 40 + sn] = (short)f2bf(av.z);
    sA[(tg * 4 + 3) * 40 + sn] = (short)f2bf(av.w);

    __builtin_amdgcn_sched_barrier(0);
    asm volatile("s_waitcnt vmcnt(0) lgkmcnt(0)" ::: "memory");
    wg_barrier();

    bf16x8 bf0 = *(const bf16x8*)&sA[(0 * 16 + fr) * 40 + fk];
    bf16x8 bf1 = *(const bf16x8*)&sA[(1 * 16 + fr) * 40 + fk];
#pragma unroll
    for (int mb = 0; mb < 4; ++mb) {
      bf16x8 af = *(const bf16x8*)&sV[1][w * 2048 + mb * 512 + fr * 32 + pq8];
      acc[mb][0] = __builtin_amdgcn_mfma_f32_16x16x32_bf16(af, bf0, acc[mb][0], 0, 0, 0);
      acc[mb][1] = __builtin_amdgcn_mfma_f32_16x16x32_bf16(af, bf1, acc[mb][1], 0, 0, 0);
    }
  }

  // epilogue: partial R for this ny
#pragma unroll
  for (int mb = 0; mb < 4; ++mb)
#pragma unroll
    for (int tb = 0; tb < 2; ++tb) {
      const int t = t0 + tb * 16 + fr;
#pragma unroll
      for (int r = 0; r < 4; ++r) {
        const int d = w * 64 + mb * 16 + q * 4 + r;
        Rpart[(((size_t)b * 4 + ny) * DD + d) * TT + t] = acc[mb][tb][r];
      }
    }
}

// ---------------- K4: R_ top = sum of 4 R partials; bottom = Q copy ----------------
// XCD-affine: block lin -> b = lin&7 matches K3's Rpart[b] producer XCD -> L2 hits.
__global__ __launch_bounds__(256) void combine(const float* __restrict__ Rpart,
                                               const float* __restrict__ Qp,
                                               float* __restrict__ out) {
  const int lin = blockIdx.x;
  const int b = lin & 7;
  const int d = lin >> 3;          // 0..511
  const int t = threadIdx.x * 4;
  if (d < 256) {
    float4 s0 = *(const float4*)(Rpart + (((size_t)b * 4 + 0) * DD + d) * TT + t);
    float4 s1 = *(const float4*)(Rpart + (((size_t)b * 4 + 1) * DD + d) * TT + t);
    float4 s2 = *(const float4*)(Rpart + (((size_t)b * 4 + 2) * DD + d) * TT + t);
    float4 s3 = *(const float4*)(Rpart + (((size_t)b * 4 + 3) * DD + d) * TT + t);
    float4 r = make_float4(s0.x + s1.x + s2.x + s3.x, s0.y + s1.y + s2.y + s3.y,
                           s0.z + s1.z + s2.z + s3.z, s0.w + s1.w + s2.w + s3.w);
    *(float4*)(out + ((size_t)b * 512 + d) * TT + t) = r;
  } else {
    float4 v = *(const float4*)(Qp + ((size_t)b * 256 + (d - 256)) * TT + t);
    *(float4*)(out + ((size_t)b * 512 + d) * TT + t) = v;
  }
}

// =================== fp32 fallback path (ws too small) ===================
__global__ __launch_bounds__(256) void gemm_scores_fp32(const float* __restrict__ Kp,
                                                        const float* __restrict__ Qp,
                                                        float* __restrict__ S) {
  const int b = blockIdx.z;
  const int n0 = blockIdx.y * 128;
  const int t0 = blockIdx.x * 128;
  const int tid = threadIdx.x;
  const int tx = tid & 15, ty = tid >> 4;
  __shared__ float Kt[8][128];
  __shared__ float Qt[8][128];
  float acc[8][8];
#pragma unroll
  for (int i = 0; i < 8; ++i)
#pragma unroll
    for (int j = 0; j < 8; ++j) acc[i][j] = 0.f;
  const int lin = tid * 4;
  const int lkk = lin >> 7, lcol = lin & 127;
  const float* Kbase = Kp + (size_t)b * DD * NN;
  const float* Qbase = Qp + (size_t)b * DD * TT;
  for (int dd0 = 0; dd0 < DD; dd0 += 8) {
    float4 kv = *(const float4*)(Kbase + (size_t)(dd0 + lkk) * NN + n0 + lcol);
    float4 qv = *(const float4*)(Qbase + (size_t)(dd0 + lkk) * TT + t0 + lcol);
    __syncthreads();
    *(float4*)&Kt[lkk][lcol] = kv;
    *(float4*)&Qt[lkk][lcol] = qv;
    __syncthreads();
#pragma unroll
    for (int kk = 0; kk < 8; ++kk) {
      float4 a0 = *(float4*)&Kt[kk][ty * 4];
      float4 a1 = *(float4*)&Kt[kk][64 + ty * 4];
      float4 b0 = *(float4*)&Qt[kk][tx * 4];
      float4 b1 = *(float4*)&Qt[kk][64 + tx * 4];
      float av[8] = {a0.x, a0.y, a0.z, a0.w, a1.x, a1.y, a1.z, a1.w};
      float bv[8] = {b0.x, b0.y, b0.z, b0.w, b1.x, b1.y, b1.z, b1.w};
#pragma unroll
      for (int i = 0; i < 8; ++i)
#pragma unroll
        for (int j = 0; j < 8; ++j) acc[i][j] += av[i] * bv[j];
    }
  }
#pragma unroll
  for (int i = 0; i < 8; ++i) {
    int r = n0 + ((i < 4) ? (ty * 4 + i) : (64 + ty * 4 + i - 4));
    float* dst = S + ((size_t)b * NN + r) * TT + t0;
    *(float4*)(dst + tx * 4) = make_float4(acc[i][0] * SCALE, acc[i][1] * SCALE, acc[i][2] * SCALE, acc[i][3] * SCALE);
    *(float4*)(dst + 64 + tx * 4) = make_float4(acc[i][4] * SCALE, acc[i][5] * SCALE, acc[i][6] * SCALE, acc[i][7] * SCALE);
  }
}

__global__ __launch_bounds__(256) void stats_partial_fb(const float* __restrict__ S,
                                                        float* __restrict__ mPart,
                                                        float* __restrict__ lPart,
                                                        int* __restrict__ iPart) {
  const int tid = threadIdx.x;
  const int tx = tid & 63, ty = tid >> 6;
  const int b = blockIdx.z;
  const int t = blockIdx.x * 64 + tx;
  const int nbase = blockIdx.y * 512;
  float m = -FLT_MAX, l = 0.f;
  int idx = 0;
  const float* col = S + (size_t)b * NN * TT + t;
  for (int n = nbase + ty; n < nbase + 512; n += 4) {
    float s = col[(size_t)n * TT];
    if (s > m) { l = l * __expf(m - s) + 1.0f; m = s; idx = n; }
    else        l += __expf(s - m);
  }
  __shared__ float sm[4][64], sl[4][64];
  __shared__ int si[4][64];
  sm[ty][tx] = m; sl[ty][tx] = l; si[ty][tx] = idx;
  __syncthreads();
  if (ty == 0) {
#pragma unroll
    for (int k = 1; k < 4; ++k) {
      float m2 = sm[k][tx], l2 = sl[k][tx];
      int i2 = si[k][tx];
      if (m2 > m)       { l = l * __expf(m - m2) + l2; m = m2; idx = i2; }
      else if (m2 == m) { l += l2; idx = min(idx, i2); }
      else              { l += l2 * __expf(m2 - m); }
    }
    size_t p = (size_t)(b * 8 + blockIdx.y) * TT + t;
    mPart[p] = m; lPart[p] = l; iPart[p] = idx;
  }
}

__global__ __launch_bounds__(256) void stats_final_fb(const float* __restrict__ mPart,
                                                      const float* __restrict__ lPart,
                                                      const int* __restrict__ iPart,
                                                      float* __restrict__ mArr,
                                                      float* __restrict__ rlArr,
                                                      float* __restrict__ outMax) {
  int col = blockIdx.x * 256 + threadIdx.x;
  int b = col >> 10, t = col & 1023;
  float m = -FLT_MAX, l = 0.f;
  int idx = 0;
#pragma unroll
  for (int c = 0; c < 8; ++c) {
    size_t p = (size_t)(b * 8 + c) * TT + t;
    float m2 = mPart[p], l2 = lPart[p];
    int i2 = iPart[p];
    if (m2 > m)       { l = l * __expf(m - m2) + l2; m = m2; idx = i2; }
    else if (m2 == m) { l += l2; idx = min(idx, i2); }
    else              { l += l2 * __expf(m2 - m); }
  }
  mArr[col] = m;
  rlArr[col] = 1.0f / l;
  outMax[col] = (float)idx;
}

__global__ __launch_bounds__(256) void normalize_fb(float* __restrict__ A,
                                                    const float* __restrict__ mArr,
                                                    const float* __restrict__ rlArr) {
  int g = blockIdx.x * 256 + threadIdx.x;
  float4 s = ((const float4*)A)[g];
  int e = g * 4;
  int t0 = e & 1023;
  int row = e >> 10;
  int b = row >> 12;
  int cb = (b << 10) + t0;
  float4 r;
  r.x = __expf(s.x - mArr[cb + 0]) * rlArr[cb + 0];
  r.y = __expf(s.y - mArr[cb + 1]) * rlArr[cb + 1];
  r.z = __expf(s.z - mArr[cb + 2]) * rlArr[cb + 2];
  r.w = __expf(s.w - mArr[cb + 3]) * rlArr[cb + 3];
  ((float4*)A)[g] = r;
}

__global__ __launch_bounds__(256) void gemm_out_fp32(const float* __restrict__ Vp,
                                                     const float* __restrict__ A,
                                                     float* __restrict__ Rout) {
  const int b = blockIdx.z;
  const int m0 = blockIdx.y * 64;
  const int t0 = blockIdx.x * 128;
  const int tid = threadIdx.x;
  const int tx = tid & 15, ty = tid >> 4;
  __shared__ float Vt[16][68];
  __shared__ float At[16][128];
  float acc[4][8];
#pragma unroll
  for (int i = 0; i < 4; ++i)
#pragma unroll
    for (int j = 0; j < 8; ++j) acc[i][j] = 0.f;
  const float* Vbase = Vp + (size_t)b * DD * NN;
  const float* Abase = A + (size_t)b * NN * TT;
  const int vmm = tid >> 2, vkk = (tid & 3) * 4;
  const int akk = tid >> 5, att = (tid * 4) & 127;
  for (int nn0 = 0; nn0 < NN; nn0 += 16) {
    float4 vv = *(const float4*)(Vbase + (size_t)(m0 + vmm) * NN + nn0 + vkk);
    float4 a0 = *(const float4*)(Abase + (size_t)(nn0 + akk) * TT + t0 + att);
    float4 a1 = *(const float4*)(Abase + (size_t)(nn0 + akk + 8) * TT + t0 + att);
    __syncthreads();
    Vt[vkk + 0][vmm] = vv.x; Vt[vkk + 1][vmm] = vv.y;
    Vt[vkk + 2][vmm] = vv.z; Vt[vkk + 3][vmm] = vv.w;
    *(float4*)&At[akk][att] = a0;
    *(float4*)&At[akk + 8][att] = a1;
    __syncthreads();
#pragma unroll
    for (int kk = 0; kk < 16; ++kk) {
      float4 a4 = *(float4*)&Vt[kk][ty * 4];
      float4 b0 = *(float4*)&At[kk][tx * 4];
      float4 b1 = *(float4*)&At[kk][64 + tx * 4];
      float av[4] = {a4.x, a4.y, a4.z, a4.w};
      float bv[8] = {b0.x, b0.y, b0.z, b0.w, b1.x, b1.y, b1.z, b1.w};
#pragma unroll
      for (int i = 0; i < 4; ++i)
#pragma unroll
        for (int j = 0; j < 8; ++j) acc[i][j] += av[i] * bv[j];
    }
  }
#pragma unroll
  for (int i = 0; i < 4; ++i) {
    int r = m0 + ty * 4 + i;
    float* dst = Rout + (size_t)b * (2 * DD) * TT + (size_t)r * TT + t0;
    *(float4*)(dst + tx * 4) = make_float4(acc[i][0], acc[i][1], acc[i][2], acc[i][3]);
    *(float4*)(dst + 64 + tx * 4) = make_float4(acc[i][4], acc[i][5], acc[i][6], acc[i][7]);
  }
}

__global__ __launch_bounds__(256) void qcopy(const float* __restrict__ Qp,
                                             float* __restrict__ out) {
  int g = blockIdx.x * 256 + threadIdx.x;
  int e = g * 4;
  int t0 = e & 1023;
  int row = e >> 10;
  int dd = row & 255, b = row >> 8;
  float4 v = ((const float4*)Qp)[g];
  *(float4*)(out + (size_t)b * 512 * TT + (size_t)(256 + dd) * TT + t0) = v;
}

extern "C" void kernel_launch(void* const* d_in, const int* in_sizes, int n_in,
                              void* d_out, int out_size, void* d_ws, size_t ws_size,
                              hipStream_t stream) {
  const float* Kp = (const float*)d_in[0];
  const float* Vp = (const float*)d_in[1];
  const float* Qp = (const float*)d_in[2];
  float* out = (float*)d_out;
  float* R_ = out;
  float* A = out + 4194304;
  float* outMax = out + 4194304 + 33554432;

  char* wsb = (char*)d_ws;
  float* mPart = (float*)(wsb + MPART_OFF);
  float* lPart = (float*)(wsb + LPART_OFF);
  int*   iPart = (int*)(wsb + IPART_OFF);
  float* mArr  = (float*)(wsb + MARR_OFF);
  float* rlArr = (float*)(wsb + RLARR_OFF);

  const bool fast = (ws_size >= WS_NEED);

  if (fast) {
    unsigned short* KtHi = (unsigned short*)(wsb + KT_HI_OFF);
    unsigned short* KtLo = (unsigned short*)(wsb + KT_LO_OFF);
    unsigned short* QtHi = (unsigned short*)(wsb + QT_HI_OFF);
    unsigned short* QtLo = (unsigned short*)(wsb + QT_LO_OFF);
    unsigned short* Vh   = (unsigned short*)(wsb + VH_OFF);
    float* Rpart = (float*)(wsb + RPART_OFF);   // aliases Kt (dead after gemm_scores)

    convert_all<<<dim3(336, 4, BB), 256, 0, stream>>>(Kp, Qp, Vp, KtHi, KtLo, QtHi, QtLo, Vh);
    gemm_scores_mfma<<<dim3(TT / 128, NN / 128, BB), 256, 0, stream>>>(
        KtHi, KtLo, QtHi, QtLo, A, mPart, lPart, iPart);
    gemm_out_fused2<<<dim3(TT / 32, 4, BB), 256, 0, stream>>>(
        Vh, A, mPart, lPart, iPart, Rpart, outMax);
    combine<<<dim3(4096), 256, 0, stream>>>(Rpart, Qp, R_);
  } else {
    gemm_scores_fp32<<<dim3(TT / 128, NN / 128, BB), 256, 0, stream>>>(Kp, Qp, A);
    stats_partial_fb<<<dim3(TT / 64, NN / 512, BB), 256, 0, stream>>>(A, mPart, lPart, iPart);
    stats_final_fb<<<dim3(32), 256, 0, stream>>>(mPart, lPart, iPart, mArr, rlArr, outMax);
    normalize_fb<<<dim3((BB * NN * TT / 4) / 256), 256, 0, stream>>>(A, mArr, rlArr);
    gemm_out_fp32<<<dim3(TT / 128, DD / 64, BB), 256, 0, stream>>>(Vp, A, R_);
    qcopy<<<dim3((BB * DD * TT / 4) / 256), 256, 0, stream>>>(Qp, R_);
  }
}